// Round 3
// baseline (15535.986 us; speedup 1.0000x reference)
//
#include <hip/hip_runtime.h>
#include <hip/hip_bf16.h>

#define L_LEN 39904
#define RCH 120
#define SCH 240
#define CMEL 80
#define NQO 256
#define NBLK 16
#define KUP 800
#define TT 64

// ---- workspace layout (float elements) ----
constexpr size_t OFF_COND = 0;                                    // 80*L
constexpr size_t OFF_RESA = OFF_COND + (size_t)CMEL * L_LEN;      // 120*L
constexpr size_t OFF_RESB = OFF_RESA + (size_t)RCH * L_LEN;       // 120*L
constexpr size_t OFF_SKIP = OFF_RESB + (size_t)RCH * L_LEN;       // 240*L
constexpr size_t OFF_WZ   = OFF_SKIP + (size_t)SCH * L_LEN;       // 921600
constexpr size_t OFF_WC   = OFF_WZ  + (size_t)NBLK * RCH * SCH * 2; // 307200
constexpr size_t OFF_WSK  = OFF_WC  + (size_t)NBLK * CMEL * SCH;    // 460800
constexpr size_t OFF_WR   = OFF_WSK + (size_t)NBLK * RCH * SCH;     // 230400
constexpr size_t OFF_BZ   = OFF_WR  + (size_t)NBLK * RCH * RCH;     // 3840
constexpr size_t OFF_WH1  = OFF_BZ  + (size_t)NBLK * SCH;           // 61440
constexpr size_t OFF_WH2  = OFF_WH1 + (size_t)SCH * NQO;            // 65536
constexpr size_t OFF_UPWT = OFF_WH2 + (size_t)NQO * NQO;            // 5120000

// ---- weight permute kernels: all to [..][c][o] so per-c chunks are contiguous ----
__global__ void k_prep_wz(const float* __restrict__ src, float* __restrict__ dst) {
    int i = blockIdx.x * 256 + threadIdx.x;
    if (i >= NBLK * RCH * SCH * 2) return;
    int k = i & 1; int rest = i >> 1;
    int o = rest % SCH; rest /= SCH;
    int c = rest % RCH; int blk = rest / RCH;
    dst[i] = src[((size_t)(blk * SCH + o) * RCH + c) * 2 + k];
}
__global__ void k_prep_wcond(const float* __restrict__ src, float* __restrict__ dst) {
    int i = blockIdx.x * 256 + threadIdx.x;
    if (i >= NBLK * CMEL * SCH) return;
    int o = i % SCH; int m = (i / SCH) % CMEL; int blk = i / (SCH * CMEL);
    dst[i] = src[(size_t)(blk * SCH + o) * CMEL + m];
}
__global__ void k_prep_wskip(const float* __restrict__ src, float* __restrict__ dst) {
    int i = blockIdx.x * 256 + threadIdx.x;
    if (i >= NBLK * RCH * SCH) return;
    int o = i % SCH; int c = (i / SCH) % RCH; int blk = i / (SCH * RCH);
    dst[i] = src[(size_t)(blk * SCH + o) * RCH + c];
}
__global__ void k_prep_wres(const float* __restrict__ src, float* __restrict__ dst) {
    int i = blockIdx.x * 256 + threadIdx.x;
    if (i >= NBLK * RCH * RCH) return;
    int o = i % RCH; int c = (i / RCH) % RCH; int blk = i / (RCH * RCH);
    dst[i] = src[(size_t)(blk * RCH + o) * RCH + c];
}
__global__ void k_prep_bz(const float* __restrict__ cb, const float* __restrict__ qb,
                          float* __restrict__ dst) {
    int i = blockIdx.x * 256 + threadIdx.x;
    if (i >= NBLK * SCH) return;
    dst[i] = cb[i] + qb[i];
}
__global__ void k_prep_h1(const float* __restrict__ src, float* __restrict__ dst) {
    int i = blockIdx.x * 256 + threadIdx.x;
    if (i >= SCH * NQO) return;
    int o = i % NQO; int c = i / NQO;
    dst[i] = src[(size_t)o * SCH + c];
}
__global__ void k_prep_h2(const float* __restrict__ src, float* __restrict__ dst) {
    int i = blockIdx.x * 256 + threadIdx.x;
    if (i >= NQO * NQO) return;
    int o = i % NQO; int c = i / NQO;
    dst[i] = src[(size_t)o * NQO + c];
}
// up_w (80,80,800): transpose (r=o*80+c, k) 6400x800 -> dst[k][r]
__global__ __launch_bounds__(256) void k_transpose_up(const float* __restrict__ src,
                                                      float* __restrict__ dst) {
    __shared__ float tile[32][33];
    int tx = threadIdx.x & 31, ty = threadIdx.x >> 5;  // 32x8
    int r0 = blockIdx.y * 32, k0 = blockIdx.x * 32;
    #pragma unroll
    for (int i = 0; i < 4; i++) {
        int r = r0 + ty + 8 * i;
        tile[ty + 8 * i][tx] = src[(size_t)r * KUP + k0 + tx];
    }
    __syncthreads();
    #pragma unroll
    for (int i = 0; i < 4; i++) {
        int k = k0 + ty + 8 * i;
        dst[(size_t)k * 6400 + r0 + tx] = tile[tx][ty + 8 * i];
    }
}

__global__ void k_res_init(const float* __restrict__ wav, const float* __restrict__ in_w,
                           const float* __restrict__ in_b, float* __restrict__ res) {
    int i = blockIdx.x * 256 + threadIdx.x;
    if (i >= RCH * L_LEN) return;
    int c = i / L_LEN, t = i % L_LEN;
    res[i] = wav[t] * in_w[c] + in_b[c];
}

// ---- upsample (transposed conv): one phase p per block; taps k = r+256j ----
__global__ __launch_bounds__(128) void k_upsample(const float* __restrict__ mel,
        const float* __restrict__ upwt, const float* __restrict__ up_b,
        float* __restrict__ cond) {
    __shared__ float wl[80 * 81];
    int p = blockIdx.x, chunk = blockIdx.y, tid = threadIdx.x;
    int r = (256 - ((p + 1) & 255)) & 255;
    int J = 3 + ((r < 32) ? 1 : 0);
    int s0 = chunk * 52;
    float acc[52];
    #pragma unroll
    for (int s = 0; s < 52; s++) acc[s] = 0.f;
    int o = tid;
    for (int j = 0; j < J; j++) {
        __syncthreads();
        int k = r + 256 * j;
        for (int idx = tid; idx < 6400; idx += 128) {
            int oo = idx / 80, cc = idx % 80;
            wl[oo * 81 + cc] = upwt[(size_t)k * 6400 + idx];
        }
        __syncthreads();
        if (o < 80) {
            for (int c = 0; c < 80; c++) {
                float w = wl[o * 81 + c];
                const float* mp = mel + c * 160 + (1 + j + s0);  // wave-uniform -> s_load
                #pragma unroll
                for (int s = 0; s < 52; s++) acc[s] += w * mp[s];
            }
        }
    }
    if (o < 80) {
        float b = up_b[o];
        for (int s = 0; s < 52; s++) {
            int t = p + 256 * (s0 + s);
            if (t < L_LEN) cond[(size_t)o * L_LEN + t] = acc[s] + b;
        }
    }
}

// ---- one WaveNet block: z -> h -> skip+= -> res_out ----
__global__ __launch_bounds__(256) void k_block(
        const float* __restrict__ cond, const float* __restrict__ res_in,
        float* __restrict__ res_out, float* __restrict__ skip,
        const float* __restrict__ Wz, const float* __restrict__ Wc,
        const float* __restrict__ Wsk, const float* __restrict__ Wr,
        const float* __restrict__ bz, const float* __restrict__ skip_b,
        const float* __restrict__ res_b, int blk, int dil, int first) {
    __shared__ float s_cur[RCH * TT];
    __shared__ float s_ph[RCH * TT];  // past res, then reused for h
    const int tid = threadIdx.x;
    const int t0 = blockIdx.x * TT;
    const int l = tid & 63;
    const int w = __builtin_amdgcn_readfirstlane(tid >> 6);
    const int t = t0 + l;
    for (int idx = tid; idx < RCH * TT; idx += 256) {
        int c = idx >> 6, j = idx & 63;
        int tc = t0 + j;
        s_cur[idx] = (tc < L_LEN) ? res_in[(size_t)c * L_LEN + tc] : 0.f;
        int tp = tc - dil;
        s_ph[idx] = (tp >= 0 && tp < L_LEN) ? res_in[(size_t)c * L_LEN + tp] : 0.f;
    }
    __syncthreads();
    float hreg[4][8];
    #pragma unroll
    for (int q = 0; q < 4; q++) {
        int cid = w + 4 * q;  // 120 (za,zb) pairs in chunks of 8 -> 15 chunks
        if (cid < 15) {
            int pb = cid * 8;
            float za[8], zb[8];
            #pragma unroll
            for (int j = 0; j < 8; j++) {
                za[j] = bz[blk * SCH + pb + j];
                zb[j] = bz[blk * SCH + 120 + pb + j];
            }
            for (int c = 0; c < RCH; c++) {
                float va = s_ph[c * TT + l];
                float vb = s_cur[c * TT + l];
                const float* wa = Wz + (((size_t)(blk * RCH + c)) * SCH + pb) * 2;  // uniform -> s_load
                #pragma unroll
                for (int j = 0; j < 8; j++) {
                    za[j] += va * wa[2 * j] + vb * wa[2 * j + 1];
                    zb[j] += va * wa[240 + 2 * j] + vb * wa[240 + 2 * j + 1];
                }
            }
            for (int m = 0; m < CMEL; m++) {
                float vc = cond[(size_t)m * L_LEN + t0 + l];
                const float* ka = Wc + ((size_t)(blk * CMEL + m)) * SCH + pb;
                #pragma unroll
                for (int j = 0; j < 8; j++) {
                    za[j] += vc * ka[j];
                    zb[j] += vc * ka[120 + j];
                }
            }
            #pragma unroll
            for (int j = 0; j < 8; j++) {
                float sg = 1.f / (1.f + expf(-zb[j]));
                hreg[q][j] = tanhf(za[j]) * sg;
            }
        }
    }
    __syncthreads();  // all reads of s_ph (past) done
    #pragma unroll
    for (int q = 0; q < 4; q++) {
        int cid = w + 4 * q;
        if (cid < 15) {
            int pb = cid * 8;
            #pragma unroll
            for (int j = 0; j < 8; j++) s_ph[(pb + j) * TT + l] = hreg[q][j];
        }
    }
    __syncthreads();
    // skip accumulation: 240 outputs, 15 chunks of 16
    #pragma unroll
    for (int q = 0; q < 4; q++) {
        int cid = w + 4 * q;
        if (cid >= 15) continue;
        int ob = cid * 16;
        float acc[16];
        #pragma unroll
        for (int j = 0; j < 16; j++) acc[j] = skip_b[blk * SCH + ob + j];
        for (int c = 0; c < RCH; c++) {
            float hv = s_ph[c * TT + l];
            const float* ww = Wsk + ((size_t)(blk * RCH + c)) * SCH + ob;
            #pragma unroll
            for (int j = 0; j < 16; j++) acc[j] += hv * ww[j];
        }
        if (t < L_LEN) {
            #pragma unroll
            for (int j = 0; j < 16; j++) {
                size_t oidx = (size_t)(ob + j) * L_LEN + t;
                float prev = first ? 0.f : skip[oidx];
                skip[oidx] = prev + acc[j];
            }
        }
    }
    // res update: 120 outputs, 8 chunks of 16 (last partial)
    #pragma unroll
    for (int q = 0; q < 2; q++) {
        int cid = w + 4 * q;
        int ob = cid * 16;
        float acc[16];
        #pragma unroll
        for (int j = 0; j < 16; j++) acc[j] = (ob + j < RCH) ? res_b[blk * RCH + ob + j] : 0.f;
        for (int c = 0; c < RCH; c++) {
            float hv = s_ph[c * TT + l];
            const float* ww = Wr + ((size_t)(blk * RCH + c)) * RCH + ob;
            #pragma unroll
            for (int j = 0; j < 16; j++) acc[j] += (ob + j < RCH) ? hv * ww[j] : 0.f;
        }
        if (t < L_LEN) {
            #pragma unroll
            for (int j = 0; j < 16; j++) {
                int oo = ob + j;
                if (oo < RCH) res_out[(size_t)oo * L_LEN + t] = s_cur[oo * TT + l] + acc[j];
            }
        }
    }
}

// ---- head: relu(skip) -> relu(h1) -> h2, f32 out ----
__global__ __launch_bounds__(256) void k_final(const float* __restrict__ skip,
        const float* __restrict__ Wh1, const float* __restrict__ Wh2,
        const float* __restrict__ h1_b, const float* __restrict__ h2_b,
        float* __restrict__ out) {
    __shared__ float X[NQO * TT];  // 64 KB
    const int tid = threadIdx.x;
    const int t0 = blockIdx.x * TT;
    const int l = tid & 63;
    const int w = __builtin_amdgcn_readfirstlane(tid >> 6);
    const int t = t0 + l;
    for (int idx = tid; idx < SCH * TT; idx += 256) {
        int c = idx >> 6, j = idx & 63;
        int tc = t0 + j;
        float v = (tc < L_LEN) ? skip[(size_t)c * L_LEN + tc] : 0.f;
        X[idx] = fmaxf(v, 0.f);
    }
    __syncthreads();
    float y1[4][16];
    #pragma unroll
    for (int q = 0; q < 4; q++) {
        int ob = (w + 4 * q) * 16;
        float acc[16];
        #pragma unroll
        for (int j = 0; j < 16; j++) acc[j] = h1_b[ob + j];
        for (int c = 0; c < SCH; c++) {
            float xv = X[c * TT + l];
            const float* ww = Wh1 + (size_t)c * NQO + ob;
            #pragma unroll
            for (int j = 0; j < 16; j++) acc[j] += xv * ww[j];
        }
        #pragma unroll
        for (int j = 0; j < 16; j++) y1[q][j] = fmaxf(acc[j], 0.f);
    }
    __syncthreads();
    #pragma unroll
    for (int q = 0; q < 4; q++) {
        int ob = (w + 4 * q) * 16;
        #pragma unroll
        for (int j = 0; j < 16; j++) X[(ob + j) * TT + l] = y1[q][j];
    }
    __syncthreads();
    #pragma unroll
    for (int q = 0; q < 4; q++) {
        int ob = (w + 4 * q) * 16;
        float acc[16];
        #pragma unroll
        for (int j = 0; j < 16; j++) acc[j] = h2_b[ob + j];
        for (int c = 0; c < NQO; c++) {
            float xv = X[c * TT + l];
            const float* ww = Wh2 + (size_t)c * NQO + ob;
            #pragma unroll
            for (int j = 0; j < 16; j++) acc[j] += xv * ww[j];
        }
        if (t < L_LEN) {
            #pragma unroll
            for (int j = 0; j < 16; j++)
                out[(size_t)(ob + j) * L_LEN + t] = acc[j];
        }
    }
}

extern "C" void kernel_launch(void* const* d_in, const int* in_sizes, int n_in,
                              void* d_out, int out_size, void* d_ws, size_t ws_size,
                              hipStream_t stream) {
    const float* wav   = (const float*)d_in[0];
    const float* mel   = (const float*)d_in[1];
    const float* up_w  = (const float*)d_in[2];
    const float* up_b  = (const float*)d_in[3];
    const float* in_w  = (const float*)d_in[4];
    const float* in_b  = (const float*)d_in[5];
    const float* bc_w  = (const float*)d_in[6];
    const float* bc_b  = (const float*)d_in[7];
    const float* bq_w  = (const float*)d_in[8];
    const float* bq_b  = (const float*)d_in[9];
    const float* bs_w  = (const float*)d_in[10];
    const float* bs_b  = (const float*)d_in[11];
    const float* br_w  = (const float*)d_in[12];
    const float* br_b  = (const float*)d_in[13];
    const float* h1_w  = (const float*)d_in[14];
    const float* h1_b  = (const float*)d_in[15];
    const float* h2_w  = (const float*)d_in[16];
    const float* h2_b  = (const float*)d_in[17];

    float* ws   = (float*)d_ws;
    float* cond = ws + OFF_COND;
    float* resA = ws + OFF_RESA;
    float* resB = ws + OFF_RESB;
    float* skip = ws + OFF_SKIP;
    float* Wz   = ws + OFF_WZ;
    float* Wc   = ws + OFF_WC;
    float* Wsk  = ws + OFF_WSK;
    float* Wr   = ws + OFF_WR;
    float* bz   = ws + OFF_BZ;
    float* Wh1  = ws + OFF_WH1;
    float* Wh2  = ws + OFF_WH2;
    float* upwt = ws + OFF_UPWT;

    // weight prep
    k_prep_wz   <<<NBLK * RCH * SCH * 2 / 256, 256, 0, stream>>>(bc_w, Wz);
    k_prep_wcond<<<NBLK * CMEL * SCH / 256,    256, 0, stream>>>(bq_w, Wc);
    k_prep_wskip<<<NBLK * RCH * SCH / 256,     256, 0, stream>>>(bs_w, Wsk);
    k_prep_wres <<<NBLK * RCH * RCH / 256,     256, 0, stream>>>(br_w, Wr);
    k_prep_bz   <<<NBLK * SCH / 256,           256, 0, stream>>>(bc_b, bq_b, bz);
    k_prep_h1   <<<SCH * NQO / 256,            256, 0, stream>>>(h1_w, Wh1);
    k_prep_h2   <<<NQO * NQO / 256,            256, 0, stream>>>(h2_w, Wh2);
    k_transpose_up<<<dim3(KUP / 32, 6400 / 32), 256, 0, stream>>>(up_w, upwt);

    k_res_init<<<(RCH * L_LEN + 255) / 256, 256, 0, stream>>>(wav, in_w, in_b, resA);
    k_upsample<<<dim3(256, 3), 128, 0, stream>>>(mel, upwt, up_b, cond);

    const int ntiles = (L_LEN + TT - 1) / TT;
    for (int i = 0; i < NBLK; i++) {
        int d = 1 << (i & 7);
        const float* rin = (i & 1) ? resB : resA;
        float* rout      = (i & 1) ? resA : resB;
        k_block<<<ntiles, 256, 0, stream>>>(cond, rin, rout, skip, Wz, Wc, Wsk, Wr,
                                            bz, bs_b, br_b, i, d, (i == 0) ? 1 : 0);
    }
    k_final<<<ntiles, 256, 0, stream>>>(skip, Wh1, Wh2, h1_b, h2_b,
                                        (float*)d_out);
}

// Round 4
// 5405.534 us; speedup vs baseline: 2.8741x; 2.8741x over previous
//
#include <hip/hip_runtime.h>
#include <hip/hip_bf16.h>

#define L_LEN 39904
#define RCH 120
#define SCH 240
#define CMEL 80
#define NQO 256
#define NBLK 16
#define KUP 800
#define TT 64

// ---- workspace layout (float elements) ----
constexpr size_t OFF_COND = 0;                                    // 80*L
constexpr size_t OFF_RESA = OFF_COND + (size_t)CMEL * L_LEN;      // 120*L
constexpr size_t OFF_RESB = OFF_RESA + (size_t)RCH * L_LEN;       // 120*L
constexpr size_t OFF_SKIP = OFF_RESB + (size_t)RCH * L_LEN;       // 240*L
constexpr size_t OFF_WZ   = OFF_SKIP + (size_t)SCH * L_LEN;       // 921600
constexpr size_t OFF_WC   = OFF_WZ  + (size_t)NBLK * RCH * SCH * 2; // 307200
constexpr size_t OFF_WSK  = OFF_WC  + (size_t)NBLK * CMEL * SCH;    // 460800
constexpr size_t OFF_WR   = OFF_WSK + (size_t)NBLK * RCH * SCH;     // 230400
constexpr size_t OFF_BZ   = OFF_WR  + (size_t)NBLK * RCH * RCH;     // 3840
constexpr size_t OFF_WH1  = OFF_BZ  + (size_t)NBLK * SCH;           // 61440
constexpr size_t OFF_WH2  = OFF_WH1 + (size_t)SCH * NQO;            // 65536
constexpr size_t OFF_UPWT = OFF_WH2 + (size_t)NQO * NQO;            // 5120000

// ---- weight permute kernels ----
// Wz: [blk][c][pair jp 0..119][4] = {past@o=jp, cur@o=jp, past@o=jp+120, cur@o=jp+120}
// so a chunk of 8 pairs is 32 contiguous floats per c -> s_load_dwordx16 pairs.
__global__ void k_prep_wz(const float* __restrict__ src, float* __restrict__ dst) {
    int i = blockIdx.x * 256 + threadIdx.x;
    if (i >= NBLK * RCH * RCH * 4) return;
    int q = i & 3; int rest = i >> 2;
    int jp = rest % RCH; rest /= RCH;
    int c = rest % RCH; int blk = rest / RCH;
    int tap = q & 1;
    int o = jp + 120 * (q >> 1);
    dst[i] = src[((size_t)(blk * SCH + o) * RCH + c) * 2 + tap];
}
// Wc: [blk][m][pair jp][2] = {w@o=jp, w@o=jp+120}
__global__ void k_prep_wcond(const float* __restrict__ src, float* __restrict__ dst) {
    int i = blockIdx.x * 256 + threadIdx.x;
    if (i >= NBLK * CMEL * RCH * 2) return;
    int q = i & 1; int rest = i >> 1;
    int jp = rest % RCH; rest /= RCH;
    int m = rest % CMEL; int blk = rest / CMEL;
    int o = jp + 120 * q;
    dst[i] = src[(size_t)(blk * SCH + o) * CMEL + m];
}
__global__ void k_prep_wskip(const float* __restrict__ src, float* __restrict__ dst) {
    int i = blockIdx.x * 256 + threadIdx.x;
    if (i >= NBLK * RCH * SCH) return;
    int o = i % SCH; int c = (i / SCH) % RCH; int blk = i / (SCH * RCH);
    dst[i] = src[(size_t)(blk * SCH + o) * RCH + c];
}
__global__ void k_prep_wres(const float* __restrict__ src, float* __restrict__ dst) {
    int i = blockIdx.x * 256 + threadIdx.x;
    if (i >= NBLK * RCH * RCH) return;
    int o = i % RCH; int c = (i / RCH) % RCH; int blk = i / (RCH * RCH);
    dst[i] = src[(size_t)(blk * RCH + o) * RCH + c];
}
__global__ void k_prep_bz(const float* __restrict__ cb, const float* __restrict__ qb,
                          float* __restrict__ dst) {
    int i = blockIdx.x * 256 + threadIdx.x;
    if (i >= NBLK * SCH) return;
    dst[i] = cb[i] + qb[i];
}
__global__ void k_prep_h1(const float* __restrict__ src, float* __restrict__ dst) {
    int i = blockIdx.x * 256 + threadIdx.x;
    if (i >= SCH * NQO) return;
    int o = i % NQO; int c = i / NQO;
    dst[i] = src[(size_t)o * SCH + c];
}
__global__ void k_prep_h2(const float* __restrict__ src, float* __restrict__ dst) {
    int i = blockIdx.x * 256 + threadIdx.x;
    if (i >= NQO * NQO) return;
    int o = i % NQO; int c = i / NQO;
    dst[i] = src[(size_t)o * NQO + c];
}
// up_w (80,80,800): transpose (r=o*80+c, k) 6400x800 -> dst[k][r]
__global__ __launch_bounds__(256) void k_transpose_up(const float* __restrict__ src,
                                                      float* __restrict__ dst) {
    __shared__ float tile[32][33];
    int tx = threadIdx.x & 31, ty = threadIdx.x >> 5;  // 32x8
    int r0 = blockIdx.y * 32, k0 = blockIdx.x * 32;
    #pragma unroll
    for (int i = 0; i < 4; i++) {
        int r = r0 + ty + 8 * i;
        tile[ty + 8 * i][tx] = src[(size_t)r * KUP + k0 + tx];
    }
    __syncthreads();
    #pragma unroll
    for (int i = 0; i < 4; i++) {
        int k = k0 + ty + 8 * i;
        dst[(size_t)k * 6400 + r0 + tx] = tile[tx][ty + 8 * i];
    }
}

__global__ void k_res_init(const float* __restrict__ wav, const float* __restrict__ in_w,
                           const float* __restrict__ in_b, float* __restrict__ res) {
    int i = blockIdx.x * 256 + threadIdx.x;
    if (i >= RCH * L_LEN) return;
    int c = i / L_LEN, t = i % L_LEN;
    res[i] = wav[t] * in_w[c] + in_b[c];
}

// ---- upsample (transposed conv): one phase p per block; taps k = r+256j ----
__global__ __launch_bounds__(128) void k_upsample(const float* __restrict__ mel,
        const float* __restrict__ upwt, const float* __restrict__ up_b,
        float* __restrict__ cond) {
    __shared__ float wl[80 * 81];
    int p = blockIdx.x, chunk = blockIdx.y, tid = threadIdx.x;
    int r = (256 - ((p + 1) & 255)) & 255;
    int J = 3 + ((r < 32) ? 1 : 0);
    int s0 = chunk * 52;
    float acc[52];
    #pragma unroll
    for (int s = 0; s < 52; s++) acc[s] = 0.f;
    int o = tid;
    for (int j = 0; j < J; j++) {
        __syncthreads();
        int k = r + 256 * j;
        for (int idx = tid; idx < 6400; idx += 128) {
            int oo = idx / 80, cc = idx % 80;
            wl[oo * 81 + cc] = upwt[(size_t)k * 6400 + idx];
        }
        __syncthreads();
        if (o < 80) {
            for (int c = 0; c < 80; c++) {
                float w = wl[o * 81 + c];
                const float* mp = mel + c * 160 + (1 + j + s0);  // wave-uniform -> s_load
                #pragma unroll
                for (int s = 0; s < 52; s++) acc[s] += w * mp[s];
            }
        }
    }
    if (o < 80) {
        float b = up_b[o];
        for (int s = 0; s < 52; s++) {
            int t = p + 256 * (s0 + s);
            if (t < L_LEN) cond[(size_t)o * L_LEN + t] = acc[s] + b;
        }
    }
}

// ---- one WaveNet block: z -> h -> skip+= -> res_out. 512 thr / 8 waves ----
__global__ __launch_bounds__(512) void k_block(
        const float* __restrict__ cond, const float* __restrict__ res_in,
        float* __restrict__ res_out, float* __restrict__ skip,
        const float* __restrict__ Wz, const float* __restrict__ Wc,
        const float* __restrict__ Wsk, const float* __restrict__ Wr,
        const float* __restrict__ bz, const float* __restrict__ skip_b,
        const float* __restrict__ res_b, int blk, int dil, int first) {
    __shared__ float s_cur[RCH * TT];
    __shared__ float s_ph[RCH * TT];  // past res, then reused for h
    const int tid = threadIdx.x;
    const int t0 = blockIdx.x * TT;
    const int l = tid & 63;
    const int w = __builtin_amdgcn_readfirstlane(tid >> 6);
    const int t = t0 + l;
    for (int idx = tid; idx < RCH * TT; idx += 512) {
        int c = idx >> 6, j = idx & 63;
        int tc = t0 + j;
        s_cur[idx] = (tc < L_LEN) ? res_in[(size_t)c * L_LEN + tc] : 0.f;
        int tp = tc - dil;
        s_ph[idx] = (tp >= 0 && tp < L_LEN) ? res_in[(size_t)c * L_LEN + tp] : 0.f;
    }
    __syncthreads();
    float hreg[2][8];
    #pragma unroll
    for (int r = 0; r < 2; r++) {
        int cid = w + 8 * r;  // 15 chunks of 8 (za,zb) pairs
        if (cid < 15) {
            int pb = cid * 8;
            float za[8], zb[8];
            #pragma unroll
            for (int j = 0; j < 8; j++) {
                za[j] = bz[blk * SCH + pb + j];
                zb[j] = bz[blk * SCH + 120 + pb + j];
            }
            const float* wzb = Wz + (size_t)blk * RCH * RCH * 4 + pb * 4;
            for (int c = 0; c < RCH; c += 2) {
                const float4* w0 = (const float4*)(wzb + (size_t)c * 480);
                const float4* w1 = (const float4*)(wzb + (size_t)c * 480 + 480);
                float va0 = s_ph[c * TT + l],       vb0 = s_cur[c * TT + l];
                float va1 = s_ph[(c + 1) * TT + l], vb1 = s_cur[(c + 1) * TT + l];
                #pragma unroll
                for (int j = 0; j < 8; j++) {
                    float4 W0 = w0[j], W1 = w1[j];
                    za[j] += va0 * W0.x + vb0 * W0.y;
                    zb[j] += va0 * W0.z + vb0 * W0.w;
                    za[j] += va1 * W1.x + vb1 * W1.y;
                    zb[j] += va1 * W1.z + vb1 * W1.w;
                }
            }
            const float* wcb = Wc + (size_t)blk * CMEL * RCH * 2 + pb * 2;
            for (int m = 0; m < CMEL; m += 2) {
                const float2* k0 = (const float2*)(wcb + (size_t)m * 240);
                const float2* k1 = (const float2*)(wcb + (size_t)m * 240 + 240);
                float vc0 = cond[(size_t)m * L_LEN + t];
                float vc1 = cond[(size_t)(m + 1) * L_LEN + t];
                #pragma unroll
                for (int j = 0; j < 8; j++) {
                    float2 K0 = k0[j], K1 = k1[j];
                    za[j] += vc0 * K0.x + vc1 * K1.x;
                    zb[j] += vc0 * K0.y + vc1 * K1.y;
                }
            }
            #pragma unroll
            for (int j = 0; j < 8; j++) {
                float sg = 1.f / (1.f + __expf(-zb[j]));
                hreg[r][j] = tanhf(za[j]) * sg;
            }
        }
    }
    __syncthreads();  // all reads of past-res done
    #pragma unroll
    for (int r = 0; r < 2; r++) {
        int cid = w + 8 * r;
        if (cid < 15) {
            int pb = cid * 8;
            #pragma unroll
            for (int j = 0; j < 8; j++) s_ph[(pb + j) * TT + l] = hreg[r][j];
        }
    }
    __syncthreads();
    // skip accumulation: 240 outputs, 15 chunks of 16
    #pragma unroll
    for (int r = 0; r < 2; r++) {
        int cid = w + 8 * r;
        if (cid >= 15) continue;
        int ob = cid * 16;
        float acc[16];
        #pragma unroll
        for (int j = 0; j < 16; j++) acc[j] = skip_b[blk * SCH + ob + j];
        const float* wkb = Wsk + (size_t)blk * RCH * SCH + ob;
        for (int c = 0; c < RCH; c += 2) {
            const float4* w0 = (const float4*)(wkb + (size_t)c * 240);
            const float4* w1 = (const float4*)(wkb + (size_t)c * 240 + 240);
            float h0 = s_ph[c * TT + l], h1v = s_ph[(c + 1) * TT + l];
            #pragma unroll
            for (int jj = 0; jj < 4; jj++) {
                float4 W0 = w0[jj], W1 = w1[jj];
                acc[4 * jj + 0] += h0 * W0.x + h1v * W1.x;
                acc[4 * jj + 1] += h0 * W0.y + h1v * W1.y;
                acc[4 * jj + 2] += h0 * W0.z + h1v * W1.z;
                acc[4 * jj + 3] += h0 * W0.w + h1v * W1.w;
            }
        }
        if (t < L_LEN) {
            #pragma unroll
            for (int j = 0; j < 16; j++) {
                size_t oidx = (size_t)(ob + j) * L_LEN + t;
                float prev = first ? 0.f : skip[oidx];
                skip[oidx] = prev + acc[j];
            }
        }
    }
    // res update: 120 outputs, 8 chunks of 16 (last chunk half)
    {
        int ob = w * 16;
        float acc[16];
        #pragma unroll
        for (int j = 0; j < 16; j++) acc[j] = (ob + j < RCH) ? res_b[blk * RCH + ob + j] : 0.f;
        const float* wrb = Wr + (size_t)blk * RCH * RCH + ob;
        for (int c = 0; c < RCH; c += 2) {
            const float4* w0 = (const float4*)(wrb + (size_t)c * 120);
            const float4* w1 = (const float4*)(wrb + (size_t)c * 120 + 120);
            float h0 = s_ph[c * TT + l], h1v = s_ph[(c + 1) * TT + l];
            #pragma unroll
            for (int jj = 0; jj < 4; jj++) {
                float4 W0 = w0[jj], W1 = w1[jj];
                acc[4 * jj + 0] += h0 * W0.x + h1v * W1.x;
                acc[4 * jj + 1] += h0 * W0.y + h1v * W1.y;
                acc[4 * jj + 2] += h0 * W0.z + h1v * W1.z;
                acc[4 * jj + 3] += h0 * W0.w + h1v * W1.w;
            }
        }
        if (t < L_LEN) {
            #pragma unroll
            for (int j = 0; j < 16; j++) {
                int oo = ob + j;
                if (oo < RCH) res_out[(size_t)oo * L_LEN + t] = s_cur[oo * TT + l] + acc[j];
            }
        }
    }
}

// ---- head: relu(skip) -> relu(h1) -> h2, f32 out. 512 thr ----
__global__ __launch_bounds__(512) void k_final(const float* __restrict__ skip,
        const float* __restrict__ Wh1, const float* __restrict__ Wh2,
        const float* __restrict__ h1_b, const float* __restrict__ h2_b,
        float* __restrict__ out) {
    __shared__ float X[NQO * TT];  // 64 KB
    const int tid = threadIdx.x;
    const int t0 = blockIdx.x * TT;
    const int l = tid & 63;
    const int w = __builtin_amdgcn_readfirstlane(tid >> 6);
    const int t = t0 + l;
    for (int idx = tid; idx < SCH * TT; idx += 512) {
        int c = idx >> 6, j = idx & 63;
        int tc = t0 + j;
        float v = (tc < L_LEN) ? skip[(size_t)c * L_LEN + tc] : 0.f;
        X[idx] = fmaxf(v, 0.f);
    }
    __syncthreads();
    float y1[2][16];
    #pragma unroll
    for (int r = 0; r < 2; r++) {
        int ob = (w + 8 * r) * 16;
        float acc[16];
        #pragma unroll
        for (int j = 0; j < 16; j++) acc[j] = h1_b[ob + j];
        const float* wb = Wh1 + ob;
        for (int c = 0; c < SCH; c += 2) {
            const float4* w0 = (const float4*)(wb + (size_t)c * NQO);
            const float4* w1 = (const float4*)(wb + (size_t)c * NQO + NQO);
            float x0 = X[c * TT + l], x1 = X[(c + 1) * TT + l];
            #pragma unroll
            for (int jj = 0; jj < 4; jj++) {
                float4 W0 = w0[jj], W1 = w1[jj];
                acc[4 * jj + 0] += x0 * W0.x + x1 * W1.x;
                acc[4 * jj + 1] += x0 * W0.y + x1 * W1.y;
                acc[4 * jj + 2] += x0 * W0.z + x1 * W1.z;
                acc[4 * jj + 3] += x0 * W0.w + x1 * W1.w;
            }
        }
        #pragma unroll
        for (int j = 0; j < 16; j++) y1[r][j] = fmaxf(acc[j], 0.f);
    }
    __syncthreads();
    #pragma unroll
    for (int r = 0; r < 2; r++) {
        int ob = (w + 8 * r) * 16;
        #pragma unroll
        for (int j = 0; j < 16; j++) X[(ob + j) * TT + l] = y1[r][j];
    }
    __syncthreads();
    #pragma unroll
    for (int r = 0; r < 2; r++) {
        int ob = (w + 8 * r) * 16;
        float acc[16];
        #pragma unroll
        for (int j = 0; j < 16; j++) acc[j] = h2_b[ob + j];
        const float* wb = Wh2 + ob;
        for (int c = 0; c < NQO; c += 2) {
            const float4* w0 = (const float4*)(wb + (size_t)c * NQO);
            const float4* w1 = (const float4*)(wb + (size_t)c * NQO + NQO);
            float x0 = X[c * TT + l], x1 = X[(c + 1) * TT + l];
            #pragma unroll
            for (int jj = 0; jj < 4; jj++) {
                float4 W0 = w0[jj], W1 = w1[jj];
                acc[4 * jj + 0] += x0 * W0.x + x1 * W1.x;
                acc[4 * jj + 1] += x0 * W0.y + x1 * W1.y;
                acc[4 * jj + 2] += x0 * W0.z + x1 * W1.z;
                acc[4 * jj + 3] += x0 * W0.w + x1 * W1.w;
            }
        }
        if (t < L_LEN) {
            #pragma unroll
            for (int j = 0; j < 16; j++)
                out[(size_t)(ob + j) * L_LEN + t] = acc[j];
        }
    }
}

extern "C" void kernel_launch(void* const* d_in, const int* in_sizes, int n_in,
                              void* d_out, int out_size, void* d_ws, size_t ws_size,
                              hipStream_t stream) {
    const float* wav   = (const float*)d_in[0];
    const float* mel   = (const float*)d_in[1];
    const float* up_w  = (const float*)d_in[2];
    const float* up_b  = (const float*)d_in[3];
    const float* in_w  = (const float*)d_in[4];
    const float* in_b  = (const float*)d_in[5];
    const float* bc_w  = (const float*)d_in[6];
    const float* bc_b  = (const float*)d_in[7];
    const float* bq_w  = (const float*)d_in[8];
    const float* bq_b  = (const float*)d_in[9];
    const float* bs_w  = (const float*)d_in[10];
    const float* bs_b  = (const float*)d_in[11];
    const float* br_w  = (const float*)d_in[12];
    const float* br_b  = (const float*)d_in[13];
    const float* h1_w  = (const float*)d_in[14];
    const float* h1_b  = (const float*)d_in[15];
    const float* h2_w  = (const float*)d_in[16];
    const float* h2_b  = (const float*)d_in[17];

    float* ws   = (float*)d_ws;
    float* cond = ws + OFF_COND;
    float* resA = ws + OFF_RESA;
    float* resB = ws + OFF_RESB;
    float* skip = ws + OFF_SKIP;
    float* Wz   = ws + OFF_WZ;
    float* Wc   = ws + OFF_WC;
    float* Wsk  = ws + OFF_WSK;
    float* Wr   = ws + OFF_WR;
    float* bz   = ws + OFF_BZ;
    float* Wh1  = ws + OFF_WH1;
    float* Wh2  = ws + OFF_WH2;
    float* upwt = ws + OFF_UPWT;

    // weight prep
    k_prep_wz   <<<NBLK * RCH * RCH * 4 / 256, 256, 0, stream>>>(bc_w, Wz);
    k_prep_wcond<<<NBLK * CMEL * RCH * 2 / 256, 256, 0, stream>>>(bq_w, Wc);
    k_prep_wskip<<<NBLK * RCH * SCH / 256,     256, 0, stream>>>(bs_w, Wsk);
    k_prep_wres <<<NBLK * RCH * RCH / 256,     256, 0, stream>>>(br_w, Wr);
    k_prep_bz   <<<NBLK * SCH / 256,           256, 0, stream>>>(bc_b, bq_b, bz);
    k_prep_h1   <<<SCH * NQO / 256,            256, 0, stream>>>(h1_w, Wh1);
    k_prep_h2   <<<NQO * NQO / 256,            256, 0, stream>>>(h2_w, Wh2);
    k_transpose_up<<<dim3(KUP / 32, 6400 / 32), 256, 0, stream>>>(up_w, upwt);

    k_res_init<<<(RCH * L_LEN + 255) / 256, 256, 0, stream>>>(wav, in_w, in_b, resA);
    k_upsample<<<dim3(256, 3), 128, 0, stream>>>(mel, upwt, up_b, cond);

    const int ntiles = (L_LEN + TT - 1) / TT;
    for (int i = 0; i < NBLK; i++) {
        int d = 1 << (i & 7);
        const float* rin = (i & 1) ? resB : resA;
        float* rout      = (i & 1) ? resA : resB;
        k_block<<<ntiles, 512, 0, stream>>>(cond, rin, rout, skip, Wz, Wc, Wsk, Wr,
                                            bz, bs_b, br_b, i, d, (i == 0) ? 1 : 0);
    }
    k_final<<<ntiles, 512, 0, stream>>>(skip, Wh1, Wh2, h1_b, h2_b,
                                        (float*)d_out);
}

// Round 5
// 1360.786 us; speedup vs baseline: 11.4169x; 3.9724x over previous
//
#include <hip/hip_runtime.h>

#define L_LEN 39904
#define NT 624
#define RCH 120
#define SCH 240
#define CMEL 80
#define NQO 256
#define NBLK 16
#define KUP 800

typedef unsigned short u16;
typedef __attribute__((ext_vector_type(8))) short short8;
typedef __attribute__((ext_vector_type(4))) float f32x4;

#define MFMA(a, b, c) __builtin_amdgcn_mfma_f32_16x16x32_bf16((a), (b), (c), 0, 0, 0)

__device__ __forceinline__ u16 f2bf(float f) {
    unsigned u = __float_as_uint(f);
    u += 0x7FFFu + ((u >> 16) & 1u);
    return (u16)(u >> 16);
}
__device__ __forceinline__ unsigned pack2(float a, float b) {
    return (unsigned)f2bf(a) | ((unsigned)f2bf(b) << 16);
}

// ---- ws layout (byte offsets, all 256-aligned) ----
constexpr size_t O_CONDT = 0;                       // [L][88] bf16 = 7,023,104
constexpr size_t O_RESA  = O_CONDT + 7023104;       // [L][120] f32 = 19,153,920
constexpr size_t O_RESB  = O_RESA + 19153920;
constexpr size_t O_SKIP  = O_RESB + 19153920;       // [L][240] f32 = 38,307,840
constexpr size_t O_ZFRAG = O_SKIP + 38307840;       // 16*10*16*512 bf16 = 2,621,440 B
constexpr size_t O_SKF   = O_ZFRAG + 2621440;       // 16*4*16*512 = 1,048,576 B
constexpr size_t O_RF    = O_SKF + 1048576;         // 16*4*8*512  = 524,288 B
constexpr size_t O_H1F   = O_RF + 524288;           // 8*16*512 bf16 = 131,072 B
constexpr size_t O_H2F   = O_H1F + 131072;          // 131,072 B
constexpr size_t O_UPF   = O_H2F + 131072;          // 256*10*5*512 bf16 = 13,107,200 B
constexpr size_t O_ZB    = O_UPF + 13107200;        // [16][256] f32 = 16,384 B
constexpr size_t O_SKB   = O_ZB + 16384;            // [16][240] f32 = 15,360 B

// ================= prep kernels =================
// zfrag: [blk][ks 0..9][mt 0..15][lane][8]. A[m][k]: m interleaved z-out, k = 320 inputs
__global__ void k_prep_zfrag(const float* __restrict__ bc_w, const float* __restrict__ bq_w,
                             u16* __restrict__ dst) {
    int i = blockIdx.x * 256 + threadIdx.x;
    if (i >= NBLK * 10 * 16 * 512) return;
    int jj = i & 7, lane = (i >> 3) & 63, mt = (i >> 9) & 15;
    int rest = i >> 13, ks = rest % 10, blk = rest / 10;
    int m = mt * 16 + (lane & 15);
    int k = ks * 32 + ((lane >> 4) << 3) + jj;
    float v = 0.f;
    if (m < 240) {
        int o = (m & 1) ? (m >> 1) + 120 : (m >> 1);
        if (k < 120)       v = bc_w[((size_t)(blk * 240 + o) * 120 + k) * 2 + 0];
        else if (k < 240)  v = bc_w[((size_t)(blk * 240 + o) * 120 + (k - 120)) * 2 + 1];
        else               v = bq_w[(size_t)(blk * 240 + o) * 80 + (k - 240)];
    }
    dst[i] = f2bf(v);
}
// skfrag: [blk][ks 0..3][mt 0..15][lane][8]. A[m=skip out][k=h ch]
__global__ void k_prep_skfrag(const float* __restrict__ bs_w, u16* __restrict__ dst) {
    int i = blockIdx.x * 256 + threadIdx.x;
    if (i >= NBLK * 4 * 16 * 512) return;
    int jj = i & 7, lane = (i >> 3) & 63, mt = (i >> 9) & 15;
    int rest = i >> 13, ks = rest & 3, blk = rest >> 2;
    int m = mt * 16 + (lane & 15);
    int k = ks * 32 + ((lane >> 4) << 3) + jj;
    float v = (m < 240 && k < 120) ? bs_w[(size_t)(blk * 240 + m) * 120 + k] : 0.f;
    dst[i] = f2bf(v);
}
// rfrag: [blk][ks 0..3][mt 0..7][lane][8]
__global__ void k_prep_rfrag(const float* __restrict__ br_w, u16* __restrict__ dst) {
    int i = blockIdx.x * 256 + threadIdx.x;
    if (i >= NBLK * 4 * 8 * 512) return;
    int jj = i & 7, lane = (i >> 3) & 63, mt = (i >> 9) & 7;
    int rest = i >> 12, ks = rest & 3, blk = rest >> 2;
    int m = mt * 16 + (lane & 15);
    int k = ks * 32 + ((lane >> 4) << 3) + jj;
    float v = (m < 120 && k < 120) ? br_w[(size_t)(blk * 120 + m) * 120 + k] : 0.f;
    dst[i] = f2bf(v);
}
// h1frag: [ks 0..7][mt 0..15][lane][8]; A[m][k] = h1_w[m][k], k<240
__global__ void k_prep_h1frag(const float* __restrict__ h1_w, u16* __restrict__ dst) {
    int i = blockIdx.x * 256 + threadIdx.x;
    if (i >= 8 * 16 * 512) return;
    int jj = i & 7, lane = (i >> 3) & 63, mt = (i >> 9) & 15, ks = i >> 13;
    int m = mt * 16 + (lane & 15);
    int k = ks * 32 + ((lane >> 4) << 3) + jj;
    float v = (k < 240) ? h1_w[(size_t)m * 240 + k] : 0.f;
    dst[i] = f2bf(v);
}
__global__ void k_prep_h2frag(const float* __restrict__ h2_w, u16* __restrict__ dst) {
    int i = blockIdx.x * 256 + threadIdx.x;
    if (i >= 8 * 16 * 512) return;
    int jj = i & 7, lane = (i >> 3) & 63, mt = (i >> 9) & 15, ks = i >> 13;
    int m = mt * 16 + (lane & 15);
    int k = ks * 32 + ((lane >> 4) << 3) + jj;
    dst[i] = f2bf(h2_w[(size_t)m * 256 + k]);
}
// upfrag: [p 0..255][ks 0..9][mt 0..4][lane][8]; A[m=o][k=ck], ck=(c<<2)|j, tap kk=r_p+256j
__global__ void k_prep_upfrag(const float* __restrict__ up_w, u16* __restrict__ dst) {
    int i = blockIdx.x * 256 + threadIdx.x;
    if (i >= 256 * 10 * 5 * 512) return;
    int jj = i & 7, lane = (i >> 3) & 63;
    int rest = i >> 9;
    int mt = rest % 5; rest /= 5;
    int ks = rest % 10; int p = rest / 10;
    int m = mt * 16 + (lane & 15);
    int k = ks * 32 + ((lane >> 4) << 3) + jj;   // < 320
    int c = k >> 2, j = k & 3;
    int r = (256 - ((p + 1) & 255)) & 255;
    int kk = r + 256 * j;
    float v = (m < 80 && kk < KUP) ? up_w[((size_t)m * 80 + c) * KUP + kk] : 0.f;
    dst[i] = f2bf(v);
}
// zbias: [16][256] f32, interleaved; pad 0
__global__ void k_prep_zbias(const float* __restrict__ bc_b, const float* __restrict__ bq_b,
                             float* __restrict__ dst) {
    int i = blockIdx.x * 256 + threadIdx.x;
    if (i >= NBLK * 256) return;
    int m = i & 255, blk = i >> 8;
    float v = 0.f;
    if (m < 240) {
        int o = (m & 1) ? (m >> 1) + 120 : (m >> 1);
        v = bc_b[blk * 240 + o] + bq_b[blk * 240 + o];
    }
    dst[i] = v;
}
__global__ void k_prep_skbias(const float* __restrict__ bs_b, float* __restrict__ dst) {
    int i = blockIdx.x * 256 + threadIdx.x;
    if (i >= NBLK * 240) return;
    dst[i] = bs_b[i];
}
// resT init: [L][120] f32
__global__ void k_res_initT(const float* __restrict__ wav, const float* __restrict__ in_w,
                            const float* __restrict__ in_b, float* __restrict__ resT) {
    int i = blockIdx.x * 256 + threadIdx.x;
    if (i >= L_LEN * RCH) return;
    int t = i / RCH, c = i % RCH;
    resT[i] = wav[t] * in_w[c] + in_b[c];
}

// ================= upsample (MFMA, per phase p) =================
__global__ __launch_bounds__(256) void k_up(const float* __restrict__ mel,
        const u16* __restrict__ upf, const float* __restrict__ up_b,
        u16* __restrict__ condT) {
    __shared__ u16 s_ms[64 * 328];
    const int tid = threadIdx.x, l = tid & 63, w = tid >> 6;
    const int quad = l >> 4, tloc = l & 15;
    const int p = blockIdx.x, s0 = blockIdx.y * 64;
    for (int rr = 0; rr < 16; rr++) {
        int tt = w + 4 * rr;
        int sg = s0 + tt;
        #pragma unroll
        for (int base = 0; base < 320; base += 64) {
            int ck = base + l;
            int c = ck >> 2, j = ck & 3;
            int mi = 1 + j + sg;
            float v = (mi < 160) ? mel[c * 160 + mi] : 0.f;
            s_ms[tt * 328 + ck] = f2bf(v);
        }
    }
    __syncthreads();
    f32x4 acc[2][4];
    #pragma unroll
    for (int i = 0; i < 2; i++)
        #pragma unroll
        for (int n = 0; n < 4; n++) acc[i][n] = (f32x4){0.f, 0.f, 0.f, 0.f};
    const int nmt = (w == 0) ? 2 : 1;
    int mts[2]; mts[0] = w; mts[1] = 4;
    for (int ks = 0; ks < 10; ks++) {
        short8 b[4];
        int k0 = ks * 32 + quad * 8;
        #pragma unroll
        for (int n = 0; n < 4; n++)
            b[n] = *(const short8*)&s_ms[(n * 16 + tloc) * 328 + k0];
        const short8* ap = (const short8*)(upf) + ((size_t)p * 10 + ks) * 5 * 64;
        for (int i = 0; i < nmt; i++) {
            short8 a = ap[mts[i] * 64 + l];
            #pragma unroll
            for (int n = 0; n < 4; n++) acc[i][n] = MFMA(a, b[n], acc[i][n]);
        }
    }
    for (int i = 0; i < nmt; i++) {
        int o_base = mts[i] * 16 + quad * 4;  // <= 76
        float4 ub = *(const float4*)(up_b + o_base);
        float bb[4] = {ub.x, ub.y, ub.z, ub.w};
        #pragma unroll
        for (int n = 0; n < 4; n++) {
            int sg = s0 + n * 16 + tloc;
            int t = p + 256 * sg;
            if (t < L_LEN) {
                #pragma unroll
                for (int r = 0; r < 4; r++)
                    condT[(size_t)t * 88 + o_base + r] = f2bf(acc[i][n][r] + bb[r]);
            }
        }
    }
}

// ================= WaveNet block (MFMA) =================
__global__ __launch_bounds__(256) void k_block(
        const u16* __restrict__ condT, const float* __restrict__ resT_in,
        float* __restrict__ resT_out, float* __restrict__ skipT,
        const u16* __restrict__ zfrag, const u16* __restrict__ skfrag,
        const u16* __restrict__ rfrag, const float* __restrict__ zbias,
        const float* __restrict__ skbias, const float* __restrict__ resb,
        int blk, int dil, int first) {
    __shared__ u16 s_x[64 * 328];   // [t][k] bf16; k: 0-119 past, 120-239 cur, 240-319 cond
    u16* s_h = s_x;                 // aliased after barrier: [t][j] stride 136
    const int tid = threadIdx.x, l = tid & 63, w = tid >> 6;
    const int quad = l >> 4, tloc = l & 15;
    const int t0 = blockIdx.x * 64;
    // ---- stage X ----
    for (int rr = 0; rr < 16; rr++) {
        int tt = w + 4 * rr;
        int tg = t0 + tt, tp = tg - dil;
        if (l < 60) {
            float2 pv = make_float2(0.f, 0.f), cv = make_float2(0.f, 0.f);
            if (tp >= 0 && tp < L_LEN) pv = *(const float2*)(resT_in + (size_t)tp * 120 + 2 * l);
            if (tg < L_LEN)            cv = *(const float2*)(resT_in + (size_t)tg * 120 + 2 * l);
            *(unsigned*)&s_x[tt * 328 + 2 * l]       = pack2(pv.x, pv.y);
            *(unsigned*)&s_x[tt * 328 + 120 + 2 * l] = pack2(cv.x, cv.y);
        }
        if (l < 40) {
            unsigned q = 0;
            if (tg < L_LEN) q = *(const unsigned*)(condT + (size_t)tg * 88 + 2 * l);
            *(unsigned*)&s_x[tt * 328 + 240 + 2 * l] = q;
        }
    }
    __syncthreads();
    // ---- z GEMM: M=256, K=320, N=64 ----
    f32x4 acc[4][4];
    #pragma unroll
    for (int i = 0; i < 4; i++)
        #pragma unroll
        for (int n = 0; n < 4; n++) acc[i][n] = (f32x4){0.f, 0.f, 0.f, 0.f};
    for (int ks = 0; ks < 10; ks++) {
        const short8* ap = (const short8*)(zfrag) + ((size_t)blk * 10 + ks) * 16 * 64;
        short8 a[4], b[4];
        #pragma unroll
        for (int i = 0; i < 4; i++) a[i] = ap[(w * 4 + i) * 64 + l];
        int k0 = ks * 32 + quad * 8;
        #pragma unroll
        for (int n = 0; n < 4; n++)
            b[n] = *(const short8*)&s_x[(n * 16 + tloc) * 328 + k0];
        #pragma unroll
        for (int i = 0; i < 4; i++)
            #pragma unroll
            for (int n = 0; n < 4; n++) acc[i][n] = MFMA(a[i], b[n], acc[i][n]);
    }
    // ---- gating (lane-local: regs = 2 (za,zb) pairs) ----
    unsigned hu[4][4];
    #pragma unroll
    for (int i = 0; i < 4; i++) {
        int mt = w * 4 + i;
        int m_base = mt * 16 + quad * 4;
        float4 bz4 = *(const float4*)(zbias + blk * 256 + m_base);
        #pragma unroll
        for (int n = 0; n < 4; n++) {
            float za0 = acc[i][n][0] + bz4.x, zb0 = acc[i][n][1] + bz4.y;
            float za1 = acc[i][n][2] + bz4.z, zb1 = acc[i][n][3] + bz4.w;
            float h0 = tanhf(za0) / (1.f + __expf(-zb0));
            float h1 = tanhf(za1) / (1.f + __expf(-zb1));
            hu[i][n] = pack2(h0, h1);
        }
    }
    __syncthreads();  // all z reads of s_x done -> safe to alias as s_h
    #pragma unroll
    for (int i = 0; i < 4; i++) {
        int j0 = (w * 4 + i) * 8 + quad * 2;
        #pragma unroll
        for (int n = 0; n < 4; n++)
            *(unsigned*)&s_h[(n * 16 + tloc) * 136 + j0] = hu[i][n];
    }
    __syncthreads();
    // ---- skip GEMM (M=256) + res GEMM (M=128), K=128, N=64 ----
    f32x4 sacc[4][4], racc[2][4];
    #pragma unroll
    for (int i = 0; i < 4; i++)
        #pragma unroll
        for (int n = 0; n < 4; n++) sacc[i][n] = (f32x4){0.f, 0.f, 0.f, 0.f};
    #pragma unroll
    for (int i = 0; i < 2; i++)
        #pragma unroll
        for (int n = 0; n < 4; n++) racc[i][n] = (f32x4){0.f, 0.f, 0.f, 0.f};
    for (int ks = 0; ks < 4; ks++) {
        short8 b[4];
        int k0 = ks * 32 + quad * 8;
        #pragma unroll
        for (int n = 0; n < 4; n++)
            b[n] = *(const short8*)&s_h[(n * 16 + tloc) * 136 + k0];
        const short8* sap = (const short8*)(skfrag) + ((size_t)blk * 4 + ks) * 16 * 64;
        const short8* rap = (const short8*)(rfrag) + ((size_t)blk * 4 + ks) * 8 * 64;
        #pragma unroll
        for (int i = 0; i < 4; i++) {
            short8 a = sap[(w * 4 + i) * 64 + l];
            #pragma unroll
            for (int n = 0; n < 4; n++) sacc[i][n] = MFMA(a, b[n], sacc[i][n]);
        }
        #pragma unroll
        for (int i = 0; i < 2; i++) {
            short8 a = rap[(w * 2 + i) * 64 + l];
            #pragma unroll
            for (int n = 0; n < 4; n++) racc[i][n] = MFMA(a, b[n], racc[i][n]);
        }
    }
    // ---- skip epilogue: f32 RMW in [L][240] ----
    #pragma unroll
    for (int i = 0; i < 4; i++) {
        int m_base = (w * 4 + i) * 16 + quad * 4;
        if (m_base >= 240) continue;
        float4 sb4 = *(const float4*)(skbias + blk * 240 + m_base);
        #pragma unroll
        for (int n = 0; n < 4; n++) {
            int t = t0 + n * 16 + tloc;
            if (t >= L_LEN) continue;
            float* p = skipT + (size_t)t * 240 + m_base;
            float4 o;
            if (first) { o.x = 0.f; o.y = 0.f; o.z = 0.f; o.w = 0.f; }
            else o = *(const float4*)p;
            o.x += sacc[i][n][0] + sb4.x;
            o.y += sacc[i][n][1] + sb4.y;
            o.z += sacc[i][n][2] + sb4.z;
            o.w += sacc[i][n][3] + sb4.w;
            *(float4*)p = o;
        }
    }
    // ---- res epilogue: res_out = res_in + Wr h + b, [L][120] ----
    #pragma unroll
    for (int i = 0; i < 2; i++) {
        int m_base = (w * 2 + i) * 16 + quad * 4;
        if (m_base >= 120) continue;
        float4 rb4 = *(const float4*)(resb + blk * 120 + m_base);
        #pragma unroll
        for (int n = 0; n < 4; n++) {
            int t = t0 + n * 16 + tloc;
            if (t >= L_LEN) continue;
            float4 cur = *(const float4*)(resT_in + (size_t)t * 120 + m_base);
            float4 o;
            o.x = cur.x + racc[i][n][0] + rb4.x;
            o.y = cur.y + racc[i][n][1] + rb4.y;
            o.z = cur.z + racc[i][n][2] + rb4.z;
            o.w = cur.w + racc[i][n][3] + rb4.w;
            *(float4*)(resT_out + (size_t)t * 120 + m_base) = o;
        }
    }
}

// ================= head: relu(skip) -> relu(h1) -> h2 (MFMA) =================
__global__ __launch_bounds__(256) void k_final(const float* __restrict__ skipT,
        const u16* __restrict__ h1f, const u16* __restrict__ h2f,
        const float* __restrict__ h1_b, const float* __restrict__ h2_b,
        float* __restrict__ out) {
    __shared__ u16 s_m[64 * 264];  // [t][m] bf16
    const int tid = threadIdx.x, l = tid & 63, w = tid >> 6;
    const int quad = l >> 4, tloc = l & 15;
    const int t0 = blockIdx.x * 64;
    // stage relu(skip)
    for (int rr = 0; rr < 16; rr++) {
        int tt = w + 4 * rr;
        int tg = t0 + tt;
        int c0 = 4 * l;  // 0..252
        unsigned lo = 0, hi = 0;
        if (tg < L_LEN && c0 < 240) {
            float4 v = *(const float4*)(skipT + (size_t)tg * 240 + c0);
            lo = pack2(fmaxf(v.x, 0.f), fmaxf(v.y, 0.f));
            hi = pack2(fmaxf(v.z, 0.f), fmaxf(v.w, 0.f));
        }
        *(unsigned*)&s_m[tt * 264 + c0]     = lo;
        *(unsigned*)&s_m[tt * 264 + c0 + 2] = hi;
    }
    __syncthreads();
    // GEMM h1
    f32x4 acc[4][4];
    #pragma unroll
    for (int i = 0; i < 4; i++)
        #pragma unroll
        for (int n = 0; n < 4; n++) acc[i][n] = (f32x4){0.f, 0.f, 0.f, 0.f};
    for (int ks = 0; ks < 8; ks++) {
        const short8* ap = (const short8*)(h1f) + (size_t)ks * 16 * 64;
        short8 a[4], b[4];
        #pragma unroll
        for (int i = 0; i < 4; i++) a[i] = ap[(w * 4 + i) * 64 + l];
        int k0 = ks * 32 + quad * 8;
        #pragma unroll
        for (int n = 0; n < 4; n++)
            b[n] = *(const short8*)&s_m[(n * 16 + tloc) * 264 + k0];
        #pragma unroll
        for (int i = 0; i < 4; i++)
            #pragma unroll
            for (int n = 0; n < 4; n++) acc[i][n] = MFMA(a[i], b[n], acc[i][n]);
    }
    // y1 = relu(acc + b1), pack
    unsigned ylo[4][4], yhi[4][4];
    #pragma unroll
    for (int i = 0; i < 4; i++) {
        int m_base = (w * 4 + i) * 16 + quad * 4;
        float4 b1 = *(const float4*)(h1_b + m_base);
        #pragma unroll
        for (int n = 0; n < 4; n++) {
            float y0 = fmaxf(acc[i][n][0] + b1.x, 0.f);
            float y1v = fmaxf(acc[i][n][1] + b1.y, 0.f);
            float y2 = fmaxf(acc[i][n][2] + b1.z, 0.f);
            float y3 = fmaxf(acc[i][n][3] + b1.w, 0.f);
            ylo[i][n] = pack2(y0, y1v);
            yhi[i][n] = pack2(y2, y3);
        }
    }
    __syncthreads();  // all GEMM-h1 B reads done
    #pragma unroll
    for (int i = 0; i < 4; i++) {
        int m_base = (w * 4 + i) * 16 + quad * 4;
        #pragma unroll
        for (int n = 0; n < 4; n++) {
            int t = n * 16 + tloc;
            *(unsigned*)&s_m[t * 264 + m_base]     = ylo[i][n];
            *(unsigned*)&s_m[t * 264 + m_base + 2] = yhi[i][n];
        }
    }
    __syncthreads();
    // GEMM h2
    #pragma unroll
    for (int i = 0; i < 4; i++)
        #pragma unroll
        for (int n = 0; n < 4; n++) acc[i][n] = (f32x4){0.f, 0.f, 0.f, 0.f};
    for (int ks = 0; ks < 8; ks++) {
        const short8* ap = (const short8*)(h2f) + (size_t)ks * 16 * 64;
        short8 a[4], b[4];
        #pragma unroll
        for (int i = 0; i < 4; i++) a[i] = ap[(w * 4 + i) * 64 + l];
        int k0 = ks * 32 + quad * 8;
        #pragma unroll
        for (int n = 0; n < 4; n++)
            b[n] = *(const short8*)&s_m[(n * 16 + tloc) * 264 + k0];
        #pragma unroll
        for (int i = 0; i < 4; i++)
            #pragma unroll
            for (int n = 0; n < 4; n++) acc[i][n] = MFMA(a[i], b[n], acc[i][n]);
    }
    #pragma unroll
    for (int i = 0; i < 4; i++) {
        int m_base = (w * 4 + i) * 16 + quad * 4;
        float4 b2 = *(const float4*)(h2_b + m_base);
        float bb[4] = {b2.x, b2.y, b2.z, b2.w};
        #pragma unroll
        for (int n = 0; n < 4; n++) {
            int t = t0 + n * 16 + tloc;
            if (t >= L_LEN) continue;
            #pragma unroll
            for (int r = 0; r < 4; r++)
                out[(size_t)(m_base + r) * L_LEN + t] = acc[i][n][r] + bb[r];
        }
    }
}

extern "C" void kernel_launch(void* const* d_in, const int* in_sizes, int n_in,
                              void* d_out, int out_size, void* d_ws, size_t ws_size,
                              hipStream_t stream) {
    const float* wav   = (const float*)d_in[0];
    const float* mel   = (const float*)d_in[1];
    const float* up_w  = (const float*)d_in[2];
    const float* up_b  = (const float*)d_in[3];
    const float* in_w  = (const float*)d_in[4];
    const float* in_b  = (const float*)d_in[5];
    const float* bc_w  = (const float*)d_in[6];
    const float* bc_b  = (const float*)d_in[7];
    const float* bq_w  = (const float*)d_in[8];
    const float* bq_b  = (const float*)d_in[9];
    const float* bs_w  = (const float*)d_in[10];
    const float* bs_b  = (const float*)d_in[11];
    const float* br_w  = (const float*)d_in[12];
    const float* br_b  = (const float*)d_in[13];
    const float* h1_w  = (const float*)d_in[14];
    const float* h1_b  = (const float*)d_in[15];
    const float* h2_w  = (const float*)d_in[16];
    const float* h2_b  = (const float*)d_in[17];

    char* wsb = (char*)d_ws;
    u16*   condT = (u16*)(wsb + O_CONDT);
    float* resA  = (float*)(wsb + O_RESA);
    float* resB  = (float*)(wsb + O_RESB);
    float* skipT = (float*)(wsb + O_SKIP);
    u16*   zfrag = (u16*)(wsb + O_ZFRAG);
    u16*   skf   = (u16*)(wsb + O_SKF);
    u16*   rf    = (u16*)(wsb + O_RF);
    u16*   h1f   = (u16*)(wsb + O_H1F);
    u16*   h2f   = (u16*)(wsb + O_H2F);
    u16*   upf   = (u16*)(wsb + O_UPF);
    float* zb    = (float*)(wsb + O_ZB);
    float* skb   = (float*)(wsb + O_SKB);

    k_prep_zfrag <<<5120, 256, 0, stream>>>(bc_w, bq_w, zfrag);
    k_prep_skfrag<<<2048, 256, 0, stream>>>(bs_w, skf);
    k_prep_rfrag <<<1024, 256, 0, stream>>>(br_w, rf);
    k_prep_h1frag<<<256, 256, 0, stream>>>(h1_w, h1f);
    k_prep_h2frag<<<256, 256, 0, stream>>>(h2_w, h2f);
    k_prep_upfrag<<<25600, 256, 0, stream>>>(up_w, upf);
    k_prep_zbias <<<16, 256, 0, stream>>>(bc_b, bq_b, zb);
    k_prep_skbias<<<15, 256, 0, stream>>>(bs_b, skb);
    k_res_initT  <<<(L_LEN * RCH + 255) / 256, 256, 0, stream>>>(wav, in_w, in_b, resA);
    k_up<<<dim3(256, 3), 256, 0, stream>>>(mel, upf, up_b, condT);

    for (int i = 0; i < NBLK; i++) {
        int d = 1 << (i & 7);
        const float* rin = (i & 1) ? resB : resA;
        float* rout      = (i & 1) ? resA : resB;
        k_block<<<NT, 256, 0, stream>>>(condT, rin, rout, skipT, zfrag, skf, rf,
                                        zb, skb, br_b, i, d, (i == 0) ? 1 : 0);
    }
    k_final<<<NT, 256, 0, stream>>>(skipT, h1f, h2f, h1_b, h2_b, (float*)d_out);
}

// Round 6
// 948.627 us; speedup vs baseline: 16.3773x; 1.4345x over previous
//
#include <hip/hip_runtime.h>

#define L_LEN 39904
#define NT 624
#define RCH 120
#define SCH 240
#define CMEL 80
#define NQO 256
#define NBLK 16
#define KUP 800

typedef unsigned short u16;
typedef __attribute__((ext_vector_type(8))) short short8;
typedef __attribute__((ext_vector_type(4))) float f32x4;

#define MFMA(a, b, c) __builtin_amdgcn_mfma_f32_16x16x32_bf16((a), (b), (c), 0, 0, 0)

__device__ __forceinline__ u16 f2bf(float f) {
    unsigned u = __float_as_uint(f);
    u += 0x7FFFu + ((u >> 16) & 1u);
    return (u16)(u >> 16);
}
__device__ __forceinline__ unsigned pack2(float a, float b) {
    return (unsigned)f2bf(a) | ((unsigned)f2bf(b) << 16);
}

// ---- ws layout (byte offsets, all 256-aligned) ----
constexpr size_t O_CONDT = 0;                       // [L][88] bf16
constexpr size_t O_RESA  = O_CONDT + 7023104;       // [L][120] f32
constexpr size_t O_RESB  = O_RESA + 19153920;
constexpr size_t O_SKIP  = O_RESB + 19153920;       // [L][240] f32
constexpr size_t O_ZFRAG = O_SKIP + 38307840;
constexpr size_t O_SKF   = O_ZFRAG + 2621440;
constexpr size_t O_RF    = O_SKF + 1048576;
constexpr size_t O_H1F   = O_RF + 524288;
constexpr size_t O_H2F   = O_H1F + 131072;
constexpr size_t O_UPF   = O_H2F + 131072;
constexpr size_t O_ZB    = O_UPF + 13107200;
constexpr size_t O_SKB   = O_ZB + 16384;

// ================= prep kernels =================
__global__ void k_prep_zfrag(const float* __restrict__ bc_w, const float* __restrict__ bq_w,
                             u16* __restrict__ dst) {
    int i = blockIdx.x * 256 + threadIdx.x;
    if (i >= NBLK * 10 * 16 * 512) return;
    int jj = i & 7, lane = (i >> 3) & 63, mt = (i >> 9) & 15;
    int rest = i >> 13, ks = rest % 10, blk = rest / 10;
    int m = mt * 16 + (lane & 15);
    int k = ks * 32 + ((lane >> 4) << 3) + jj;
    float v = 0.f;
    if (m < 240) {
        int o = (m & 1) ? (m >> 1) + 120 : (m >> 1);
        if (k < 120)       v = bc_w[((size_t)(blk * 240 + o) * 120 + k) * 2 + 0];
        else if (k < 240)  v = bc_w[((size_t)(blk * 240 + o) * 120 + (k - 120)) * 2 + 1];
        else               v = bq_w[(size_t)(blk * 240 + o) * 80 + (k - 240)];
    }
    dst[i] = f2bf(v);
}
__global__ void k_prep_skfrag(const float* __restrict__ bs_w, u16* __restrict__ dst) {
    int i = blockIdx.x * 256 + threadIdx.x;
    if (i >= NBLK * 4 * 16 * 512) return;
    int jj = i & 7, lane = (i >> 3) & 63, mt = (i >> 9) & 15;
    int rest = i >> 13, ks = rest & 3, blk = rest >> 2;
    int m = mt * 16 + (lane & 15);
    int k = ks * 32 + ((lane >> 4) << 3) + jj;
    float v = (m < 240 && k < 120) ? bs_w[(size_t)(blk * 240 + m) * 120 + k] : 0.f;
    dst[i] = f2bf(v);
}
__global__ void k_prep_rfrag(const float* __restrict__ br_w, u16* __restrict__ dst) {
    int i = blockIdx.x * 256 + threadIdx.x;
    if (i >= NBLK * 4 * 8 * 512) return;
    int jj = i & 7, lane = (i >> 3) & 63, mt = (i >> 9) & 7;
    int rest = i >> 12, ks = rest & 3, blk = rest >> 2;
    int m = mt * 16 + (lane & 15);
    int k = ks * 32 + ((lane >> 4) << 3) + jj;
    float v = (m < 120 && k < 120) ? br_w[(size_t)(blk * 120 + m) * 120 + k] : 0.f;
    dst[i] = f2bf(v);
}
__global__ void k_prep_h1frag(const float* __restrict__ h1_w, u16* __restrict__ dst) {
    int i = blockIdx.x * 256 + threadIdx.x;
    if (i >= 8 * 16 * 512) return;
    int jj = i & 7, lane = (i >> 3) & 63, mt = (i >> 9) & 15, ks = i >> 13;
    int m = mt * 16 + (lane & 15);
    int k = ks * 32 + ((lane >> 4) << 3) + jj;
    float v = (k < 240) ? h1_w[(size_t)m * 240 + k] : 0.f;
    dst[i] = f2bf(v);
}
__global__ void k_prep_h2frag(const float* __restrict__ h2_w, u16* __restrict__ dst) {
    int i = blockIdx.x * 256 + threadIdx.x;
    if (i >= 8 * 16 * 512) return;
    int jj = i & 7, lane = (i >> 3) & 63, mt = (i >> 9) & 15, ks = i >> 13;
    int m = mt * 16 + (lane & 15);
    int k = ks * 32 + ((lane >> 4) << 3) + jj;
    dst[i] = f2bf(h2_w[(size_t)m * 256 + k]);
}
__global__ void k_prep_upfrag(const float* __restrict__ up_w, u16* __restrict__ dst) {
    int i = blockIdx.x * 256 + threadIdx.x;
    if (i >= 256 * 10 * 5 * 512) return;
    int jj = i & 7, lane = (i >> 3) & 63;
    int rest = i >> 9;
    int mt = rest % 5; rest /= 5;
    int ks = rest % 10; int p = rest / 10;
    int m = mt * 16 + (lane & 15);
    int k = ks * 32 + ((lane >> 4) << 3) + jj;
    int c = k >> 2, j = k & 3;
    int r = (256 - ((p + 1) & 255)) & 255;
    int kk = r + 256 * j;
    float v = (m < 80 && kk < KUP) ? up_w[((size_t)m * 80 + c) * KUP + kk] : 0.f;
    dst[i] = f2bf(v);
}
__global__ void k_prep_zbias(const float* __restrict__ bc_b, const float* __restrict__ bq_b,
                             float* __restrict__ dst) {
    int i = blockIdx.x * 256 + threadIdx.x;
    if (i >= NBLK * 256) return;
    int m = i & 255, blk = i >> 8;
    float v = 0.f;
    if (m < 240) {
        int o = (m & 1) ? (m >> 1) + 120 : (m >> 1);
        v = bc_b[blk * 240 + o] + bq_b[blk * 240 + o];
    }
    dst[i] = v;
}
__global__ void k_prep_skbias(const float* __restrict__ bs_b, float* __restrict__ dst) {
    int i = blockIdx.x * 256 + threadIdx.x;
    if (i >= NBLK * 240) return;
    dst[i] = bs_b[i];
}
__global__ void k_res_initT(const float* __restrict__ wav, const float* __restrict__ in_w,
                            const float* __restrict__ in_b, float* __restrict__ resT) {
    int i = blockIdx.x * 256 + threadIdx.x;
    if (i >= L_LEN * RCH) return;
    int t = i / RCH, c = i % RCH;
    resT[i] = wav[t] * in_w[c] + in_b[c];
}

// ================= upsample (MFMA, per phase p) =================
__global__ __launch_bounds__(256) void k_up(const float* __restrict__ mel,
        const u16* __restrict__ upf, const float* __restrict__ up_b,
        u16* __restrict__ condT) {
    __shared__ u16 s_ms[64 * 328];
    const int tid = threadIdx.x, l = tid & 63, w = tid >> 6;
    const int quad = l >> 4, tloc = l & 15;
    const int p = blockIdx.x, s0 = blockIdx.y * 64;
    for (int rr = 0; rr < 16; rr++) {
        int tt = w + 4 * rr;
        int sg = s0 + tt;
        #pragma unroll
        for (int base = 0; base < 320; base += 64) {
            int ck = base + l;
            int c = ck >> 2, j = ck & 3;
            int mi = 1 + j + sg;
            float v = (mi < 160) ? mel[c * 160 + mi] : 0.f;
            s_ms[tt * 328 + ck] = f2bf(v);
        }
    }
    __syncthreads();
    f32x4 acc[2][4];
    #pragma unroll
    for (int i = 0; i < 2; i++)
        #pragma unroll
        for (int n = 0; n < 4; n++) acc[i][n] = (f32x4){0.f, 0.f, 0.f, 0.f};
    const int nmt = (w == 0) ? 2 : 1;
    int mts[2]; mts[0] = w; mts[1] = 4;
    for (int ks = 0; ks < 10; ks++) {
        short8 b[4];
        int k0 = ks * 32 + quad * 8;
        #pragma unroll
        for (int n = 0; n < 4; n++)
            b[n] = *(const short8*)&s_ms[(n * 16 + tloc) * 328 + k0];
        const short8* ap = (const short8*)(upf) + ((size_t)p * 10 + ks) * 5 * 64;
        for (int i = 0; i < nmt; i++) {
            short8 a = ap[mts[i] * 64 + l];
            #pragma unroll
            for (int n = 0; n < 4; n++) acc[i][n] = MFMA(a, b[n], acc[i][n]);
        }
    }
    for (int i = 0; i < nmt; i++) {
        int o_base = mts[i] * 16 + quad * 4;
        float4 ub = *(const float4*)(up_b + o_base);
        float bb[4] = {ub.x, ub.y, ub.z, ub.w};
        #pragma unroll
        for (int n = 0; n < 4; n++) {
            int sg = s0 + n * 16 + tloc;
            int t = p + 256 * sg;
            if (t < L_LEN) {
                #pragma unroll
                for (int r = 0; r < 4; r++)
                    condT[(size_t)t * 88 + o_base + r] = f2bf(acc[i][n][r] + bb[r]);
            }
        }
    }
}

// ================= WaveNet block (MFMA, 512 thr / 8 waves) =================
__global__ __launch_bounds__(512, 4) void k_block(
        const u16* __restrict__ condT, const float* __restrict__ resT_in,
        float* __restrict__ resT_out, float* __restrict__ skipT,
        const u16* __restrict__ zfrag, const u16* __restrict__ skfrag,
        const u16* __restrict__ rfrag, const float* __restrict__ zbias,
        const float* __restrict__ skbias, const float* __restrict__ resb,
        int blk, int dil, int first) {
    __shared__ u16 s_x[64 * 328];   // [t][k]; k: 0-119 past, 120-239 cur, 240-319 cond
    u16* s_h = s_x;                 // aliased after barrier: [t][j] stride 136
    const int tid = threadIdx.x, l = tid & 63, w = tid >> 6;  // w 0..7
    const int quad = l >> 4, tloc = l & 15;
    const int t0 = blockIdx.x * 64;
    // prefetch first z A-frags before staging (latency hidden behind stage+barrier)
    const short8* zap = (const short8*)(zfrag) + (size_t)blk * 10 * 16 * 64;
    short8 a_cur[2], a_nxt[2];
    #pragma unroll
    for (int i = 0; i < 2; i++) a_cur[i] = zap[(size_t)(w * 2 + i) * 64 + l];
    // ---- stage X ----
    for (int rr = 0; rr < 8; rr++) {
        int tt = w + 8 * rr;
        int tg = t0 + tt, tp = tg - dil;
        if (l < 60) {
            float2 pv = make_float2(0.f, 0.f), cv = make_float2(0.f, 0.f);
            if (tp >= 0 && tp < L_LEN) pv = *(const float2*)(resT_in + (size_t)tp * 120 + 2 * l);
            if (tg < L_LEN)            cv = *(const float2*)(resT_in + (size_t)tg * 120 + 2 * l);
            *(unsigned*)&s_x[tt * 328 + 2 * l]       = pack2(pv.x, pv.y);
            *(unsigned*)&s_x[tt * 328 + 120 + 2 * l] = pack2(cv.x, cv.y);
        }
        if (l < 40) {
            unsigned q = 0;
            if (tg < L_LEN) q = *(const unsigned*)(condT + (size_t)tg * 88 + 2 * l);
            *(unsigned*)&s_x[tt * 328 + 240 + 2 * l] = q;
        }
    }
    __syncthreads();
    // ---- z GEMM: M=256 (2 mt/wave), K=320, N=64, prefetch pipeline ----
    f32x4 acc[2][4];
    #pragma unroll
    for (int i = 0; i < 2; i++)
        #pragma unroll
        for (int n = 0; n < 4; n++) acc[i][n] = (f32x4){0.f, 0.f, 0.f, 0.f};
    for (int ks = 0; ks < 10; ks++) {
        if (ks < 9) {
            #pragma unroll
            for (int i = 0; i < 2; i++)
                a_nxt[i] = zap[((size_t)(ks + 1) * 16 + w * 2 + i) * 64 + l];
        }
        int k0 = ks * 32 + quad * 8;
        short8 b[4];
        #pragma unroll
        for (int n = 0; n < 4; n++)
            b[n] = *(const short8*)&s_x[(n * 16 + tloc) * 328 + k0];
        #pragma unroll
        for (int i = 0; i < 2; i++)
            #pragma unroll
            for (int n = 0; n < 4; n++) acc[i][n] = MFMA(a_cur[i], b[n], acc[i][n]);
        #pragma unroll
        for (int i = 0; i < 2; i++) a_cur[i] = a_nxt[i];
    }
    // ---- gating ----
    unsigned hu[2][4];
    #pragma unroll
    for (int i = 0; i < 2; i++) {
        int m_base = (w * 2 + i) * 16 + quad * 4;
        float4 bz4 = *(const float4*)(zbias + blk * 256 + m_base);
        #pragma unroll
        for (int n = 0; n < 4; n++) {
            float za0 = acc[i][n][0] + bz4.x, zb0 = acc[i][n][1] + bz4.y;
            float za1 = acc[i][n][2] + bz4.z, zb1 = acc[i][n][3] + bz4.w;
            float h0 = tanhf(za0) / (1.f + __expf(-zb0));
            float h1 = tanhf(za1) / (1.f + __expf(-zb1));
            hu[i][n] = pack2(h0, h1);
        }
    }
    // prefetch first skip/res A-frags
    const short8* sap = (const short8*)(skfrag) + (size_t)blk * 4 * 16 * 64;
    const short8* rap = (const short8*)(rfrag) + (size_t)blk * 4 * 8 * 64;
    short8 sa_c[2], sa_n[2], ra_c, ra_n;
    #pragma unroll
    for (int i = 0; i < 2; i++) sa_c[i] = sap[(size_t)(w * 2 + i) * 64 + l];
    ra_c = rap[(size_t)w * 64 + l];
    __syncthreads();  // all z reads of s_x done -> safe to alias as s_h
    #pragma unroll
    for (int i = 0; i < 2; i++) {
        int j0 = (w * 2 + i) * 8 + quad * 2;
        #pragma unroll
        for (int n = 0; n < 4; n++)
            *(unsigned*)&s_h[(n * 16 + tloc) * 136 + j0] = hu[i][n];
    }
    __syncthreads();
    // ---- skip GEMM (2 mt/wave) + res GEMM (1 mt/wave), K=128, N=64 ----
    f32x4 sacc[2][4], racc[4];
    #pragma unroll
    for (int i = 0; i < 2; i++)
        #pragma unroll
        for (int n = 0; n < 4; n++) sacc[i][n] = (f32x4){0.f, 0.f, 0.f, 0.f};
    #pragma unroll
    for (int n = 0; n < 4; n++) racc[n] = (f32x4){0.f, 0.f, 0.f, 0.f};
    for (int ks = 0; ks < 4; ks++) {
        if (ks < 3) {
            #pragma unroll
            for (int i = 0; i < 2; i++)
                sa_n[i] = sap[((size_t)(ks + 1) * 16 + w * 2 + i) * 64 + l];
            ra_n = rap[((size_t)(ks + 1) * 8 + w) * 64 + l];
        }
        short8 b[4];
        int k0 = ks * 32 + quad * 8;
        #pragma unroll
        for (int n = 0; n < 4; n++)
            b[n] = *(const short8*)&s_h[(n * 16 + tloc) * 136 + k0];
        #pragma unroll
        for (int i = 0; i < 2; i++)
            #pragma unroll
            for (int n = 0; n < 4; n++) sacc[i][n] = MFMA(sa_c[i], b[n], sacc[i][n]);
        #pragma unroll
        for (int n = 0; n < 4; n++) racc[n] = MFMA(ra_c, b[n], racc[n]);
        #pragma unroll
        for (int i = 0; i < 2; i++) sa_c[i] = sa_n[i];
        ra_c = ra_n;
    }
    // ---- skip epilogue: f32 RMW in [L][240] ----
    #pragma unroll
    for (int i = 0; i < 2; i++) {
        int m_base = (w * 2 + i) * 16 + quad * 4;
        if (m_base >= 240) continue;
        float4 sb4 = *(const float4*)(skbias + blk * 240 + m_base);
        #pragma unroll
        for (int n = 0; n < 4; n++) {
            int t = t0 + n * 16 + tloc;
            if (t >= L_LEN) continue;
            float* p = skipT + (size_t)t * 240 + m_base;
            float4 o;
            if (first) { o.x = 0.f; o.y = 0.f; o.z = 0.f; o.w = 0.f; }
            else o = *(const float4*)p;
            o.x += sacc[i][n][0] + sb4.x;
            o.y += sacc[i][n][1] + sb4.y;
            o.z += sacc[i][n][2] + sb4.z;
            o.w += sacc[i][n][3] + sb4.w;
            *(float4*)p = o;
        }
    }
    // ---- res epilogue ----
    {
        int m_base = w * 16 + quad * 4;
        if (m_base < 120) {
            float4 rb4 = *(const float4*)(resb + blk * 120 + m_base);
            #pragma unroll
            for (int n = 0; n < 4; n++) {
                int t = t0 + n * 16 + tloc;
                if (t >= L_LEN) continue;
                float4 cur = *(const float4*)(resT_in + (size_t)t * 120 + m_base);
                float4 o;
                o.x = cur.x + racc[n][0] + rb4.x;
                o.y = cur.y + racc[n][1] + rb4.y;
                o.z = cur.z + racc[n][2] + rb4.z;
                o.w = cur.w + racc[n][3] + rb4.w;
                *(float4*)(resT_out + (size_t)t * 120 + m_base) = o;
            }
        }
    }
}

// ================= head (MFMA, 512 thr) =================
__global__ __launch_bounds__(512, 4) void k_final(const float* __restrict__ skipT,
        const u16* __restrict__ h1f, const u16* __restrict__ h2f,
        const float* __restrict__ h1_b, const float* __restrict__ h2_b,
        float* __restrict__ out) {
    __shared__ u16 s_m[64 * 264];
    const int tid = threadIdx.x, l = tid & 63, w = tid >> 6;  // w 0..7
    const int quad = l >> 4, tloc = l & 15;
    const int t0 = blockIdx.x * 64;
    // prefetch first h1 A-frags
    const short8* ap1 = (const short8*)h1f;
    short8 a_cur[2], a_nxt[2];
    #pragma unroll
    for (int i = 0; i < 2; i++) a_cur[i] = ap1[(size_t)(w * 2 + i) * 64 + l];
    // stage relu(skip)
    for (int rr = 0; rr < 8; rr++) {
        int tt = w + 8 * rr;
        int tg = t0 + tt;
        int c0 = 4 * l;
        unsigned lo = 0, hi = 0;
        if (tg < L_LEN && c0 < 240) {
            float4 v = *(const float4*)(skipT + (size_t)tg * 240 + c0);
            lo = pack2(fmaxf(v.x, 0.f), fmaxf(v.y, 0.f));
            hi = pack2(fmaxf(v.z, 0.f), fmaxf(v.w, 0.f));
        }
        *(unsigned*)&s_m[tt * 264 + c0]     = lo;
        *(unsigned*)&s_m[tt * 264 + c0 + 2] = hi;
    }
    __syncthreads();
    // GEMM h1 (2 mt/wave)
    f32x4 acc[2][4];
    #pragma unroll
    for (int i = 0; i < 2; i++)
        #pragma unroll
        for (int n = 0; n < 4; n++) acc[i][n] = (f32x4){0.f, 0.f, 0.f, 0.f};
    for (int ks = 0; ks < 8; ks++) {
        if (ks < 7) {
            #pragma unroll
            for (int i = 0; i < 2; i++)
                a_nxt[i] = ap1[((size_t)(ks + 1) * 16 + w * 2 + i) * 64 + l];
        }
        short8 b[4];
        int k0 = ks * 32 + quad * 8;
        #pragma unroll
        for (int n = 0; n < 4; n++)
            b[n] = *(const short8*)&s_m[(n * 16 + tloc) * 264 + k0];
        #pragma unroll
        for (int i = 0; i < 2; i++)
            #pragma unroll
            for (int n = 0; n < 4; n++) acc[i][n] = MFMA(a_cur[i], b[n], acc[i][n]);
        #pragma unroll
        for (int i = 0; i < 2; i++) a_cur[i] = a_nxt[i];
    }
    unsigned ylo[2][4], yhi[2][4];
    #pragma unroll
    for (int i = 0; i < 2; i++) {
        int m_base = (w * 2 + i) * 16 + quad * 4;
        float4 b1 = *(const float4*)(h1_b + m_base);
        #pragma unroll
        for (int n = 0; n < 4; n++) {
            float y0 = fmaxf(acc[i][n][0] + b1.x, 0.f);
            float y1v = fmaxf(acc[i][n][1] + b1.y, 0.f);
            float y2 = fmaxf(acc[i][n][2] + b1.z, 0.f);
            float y3 = fmaxf(acc[i][n][3] + b1.w, 0.f);
            ylo[i][n] = pack2(y0, y1v);
            yhi[i][n] = pack2(y2, y3);
        }
    }
    const short8* ap2 = (const short8*)h2f;
    #pragma unroll
    for (int i = 0; i < 2; i++) a_cur[i] = ap2[(size_t)(w * 2 + i) * 64 + l];
    __syncthreads();
    #pragma unroll
    for (int i = 0; i < 2; i++) {
        int m_base = (w * 2 + i) * 16 + quad * 4;
        #pragma unroll
        for (int n = 0; n < 4; n++) {
            int t = n * 16 + tloc;
            *(unsigned*)&s_m[t * 264 + m_base]     = ylo[i][n];
            *(unsigned*)&s_m[t * 264 + m_base + 2] = yhi[i][n];
        }
    }
    __syncthreads();
    // GEMM h2
    #pragma unroll
    for (int i = 0; i < 2; i++)
        #pragma unroll
        for (int n = 0; n < 4; n++) acc[i][n] = (f32x4){0.f, 0.f, 0.f, 0.f};
    for (int ks = 0; ks < 8; ks++) {
        if (ks < 7) {
            #pragma unroll
            for (int i = 0; i < 2; i++)
                a_nxt[i] = ap2[((size_t)(ks + 1) * 16 + w * 2 + i) * 64 + l];
        }
        short8 b[4];
        int k0 = ks * 32 + quad * 8;
        #pragma unroll
        for (int n = 0; n < 4; n++)
            b[n] = *(const short8*)&s_m[(n * 16 + tloc) * 264 + k0];
        #pragma unroll
        for (int i = 0; i < 2; i++)
            #pragma unroll
            for (int n = 0; n < 4; n++) acc[i][n] = MFMA(a_cur[i], b[n], acc[i][n]);
        #pragma unroll
        for (int i = 0; i < 2; i++) a_cur[i] = a_nxt[i];
    }
    #pragma unroll
    for (int i = 0; i < 2; i++) {
        int m_base = (w * 2 + i) * 16 + quad * 4;
        float4 b2 = *(const float4*)(h2_b + m_base);
        float bb[4] = {b2.x, b2.y, b2.z, b2.w};
        #pragma unroll
        for (int n = 0; n < 4; n++) {
            int t = t0 + n * 16 + tloc;
            if (t >= L_LEN) continue;
            #pragma unroll
            for (int r = 0; r < 4; r++)
                out[(size_t)(m_base + r) * L_LEN + t] = acc[i][n][r] + bb[r];
        }
    }
}

extern "C" void kernel_launch(void* const* d_in, const int* in_sizes, int n_in,
                              void* d_out, int out_size, void* d_ws, size_t ws_size,
                              hipStream_t stream) {
    const float* wav   = (const float*)d_in[0];
    const float* mel   = (const float*)d_in[1];
    const float* up_w  = (const float*)d_in[2];
    const float* up_b  = (const float*)d_in[3];
    const float* in_w  = (const float*)d_in[4];
    const float* in_b  = (const float*)d_in[5];
    const float* bc_w  = (const float*)d_in[6];
    const float* bc_b  = (const float*)d_in[7];
    const float* bq_w  = (const float*)d_in[8];
    const float* bq_b  = (const float*)d_in[9];
    const float* bs_w  = (const float*)d_in[10];
    const float* bs_b  = (const float*)d_in[11];
    const float* br_w  = (const float*)d_in[12];
    const float* br_b  = (const float*)d_in[13];
    const float* h1_w  = (const float*)d_in[14];
    const float* h1_b  = (const float*)d_in[15];
    const float* h2_w  = (const float*)d_in[16];
    const float* h2_b  = (const float*)d_in[17];

    char* wsb = (char*)d_ws;
    u16*   condT = (u16*)(wsb + O_CONDT);
    float* resA  = (float*)(wsb + O_RESA);
    float* resB  = (float*)(wsb + O_RESB);
    float* skipT = (float*)(wsb + O_SKIP);
    u16*   zfrag = (u16*)(wsb + O_ZFRAG);
    u16*   skf   = (u16*)(wsb + O_SKF);
    u16*   rf    = (u16*)(wsb + O_RF);
    u16*   h1f   = (u16*)(wsb + O_H1F);
    u16*   h2f   = (u16*)(wsb + O_H2F);
    u16*   upf   = (u16*)(wsb + O_UPF);
    float* zb    = (float*)(wsb + O_ZB);
    float* skb   = (float*)(wsb + O_SKB);

    k_prep_zfrag <<<5120, 256, 0, stream>>>(bc_w, bq_w, zfrag);
    k_prep_skfrag<<<2048, 256, 0, stream>>>(bs_w, skf);
    k_prep_rfrag <<<1024, 256, 0, stream>>>(br_w, rf);
    k_prep_h1frag<<<256, 256, 0, stream>>>(h1_w, h1f);
    k_prep_h2frag<<<256, 256, 0, stream>>>(h2_w, h2f);
    k_prep_upfrag<<<25600, 256, 0, stream>>>(up_w, upf);
    k_prep_zbias <<<16, 256, 0, stream>>>(bc_b, bq_b, zb);
    k_prep_skbias<<<15, 256, 0, stream>>>(bs_b, skb);
    k_res_initT  <<<(L_LEN * RCH + 255) / 256, 256, 0, stream>>>(wav, in_w, in_b, resA);
    k_up<<<dim3(256, 3), 256, 0, stream>>>(mel, upf, up_b, condT);

    for (int i = 0; i < NBLK; i++) {
        int d = 1 << (i & 7);
        const float* rin = (i & 1) ? resB : resA;
        float* rout      = (i & 1) ? resA : resB;
        k_block<<<NT, 512, 0, stream>>>(condT, rin, rout, skipT, zfrag, skf, rf,
                                        zb, skb, br_b, i, d, (i == 0) ? 1 : 0);
    }
    k_final<<<NT, 512, 0, stream>>>(skipT, h1f, h2f, h1_b, h2_b, (float*)d_out);
}

// Round 7
// 821.862 us; speedup vs baseline: 18.9034x; 1.1542x over previous
//
#include <hip/hip_runtime.h>

#define L_LEN 39904
#define NT 624
#define RCH 120
#define SCH 240
#define CMEL 80
#define NQO 256
#define NBLK 16
#define KUP 800

typedef unsigned short u16;
typedef __attribute__((ext_vector_type(8))) short short8;
typedef __attribute__((ext_vector_type(4))) float f32x4;

#define MFMA(a, b, c) __builtin_amdgcn_mfma_f32_16x16x32_bf16((a), (b), (c), 0, 0, 0)

__device__ __forceinline__ u16 f2bf(float f) {
    unsigned u = __float_as_uint(f);
    u += 0x7FFFu + ((u >> 16) & 1u);
    return (u16)(u >> 16);
}
__device__ __forceinline__ unsigned pack2(float a, float b) {
    return (unsigned)f2bf(a) | ((unsigned)f2bf(b) << 16);
}
__device__ __forceinline__ float b16tof(u16 h) {
    return __uint_as_float((unsigned)h << 16);
}
// fast gating: tanh(a)*sigmoid(b) via v_exp + v_rcp (err ~1e-7, << bf16 noise)
__device__ __forceinline__ float gate(float a, float b) {
    float ea = __expf(2.f * a);
    float th = 1.f - 2.f * __builtin_amdgcn_rcpf(ea + 1.f);
    float sg = __builtin_amdgcn_rcpf(1.f + __expf(-b));
    return th * sg;
}

// ---- ws layout (byte offsets, all 256-aligned) ----
constexpr size_t O_CONDT = 0;                       // [L][88] bf16
constexpr size_t O_RESA  = O_CONDT + 7023104;       // [L][120] f32
constexpr size_t O_RESB  = O_RESA + 19153920;
constexpr size_t O_SKIP  = O_RESB + 19153920;       // [L][240] bf16 = 19,153,920
constexpr size_t O_ZFRAG = O_SKIP + 19153920;
constexpr size_t O_SKF   = O_ZFRAG + 2621440;
constexpr size_t O_RF    = O_SKF + 1048576;
constexpr size_t O_H1F   = O_RF + 524288;
constexpr size_t O_H2F   = O_H1F + 131072;
constexpr size_t O_UPF   = O_H2F + 131072;
constexpr size_t O_ZB    = O_UPF + 13107200;
constexpr size_t O_SKB   = O_ZB + 16384;

// ================= prep kernels =================
__global__ void k_prep_zfrag(const float* __restrict__ bc_w, const float* __restrict__ bq_w,
                             u16* __restrict__ dst) {
    int i = blockIdx.x * 256 + threadIdx.x;
    if (i >= NBLK * 10 * 16 * 512) return;
    int jj = i & 7, lane = (i >> 3) & 63, mt = (i >> 9) & 15;
    int rest = i >> 13, ks = rest % 10, blk = rest / 10;
    int m = mt * 16 + (lane & 15);
    int k = ks * 32 + ((lane >> 4) << 3) + jj;
    float v = 0.f;
    if (m < 240) {
        int o = (m & 1) ? (m >> 1) + 120 : (m >> 1);
        if (k < 120)       v = bc_w[((size_t)(blk * 240 + o) * 120 + k) * 2 + 0];
        else if (k < 240)  v = bc_w[((size_t)(blk * 240 + o) * 120 + (k - 120)) * 2 + 1];
        else               v = bq_w[(size_t)(blk * 240 + o) * 80 + (k - 240)];
    }
    dst[i] = f2bf(v);
}
__global__ void k_prep_skfrag(const float* __restrict__ bs_w, u16* __restrict__ dst) {
    int i = blockIdx.x * 256 + threadIdx.x;
    if (i >= NBLK * 4 * 16 * 512) return;
    int jj = i & 7, lane = (i >> 3) & 63, mt = (i >> 9) & 15;
    int rest = i >> 13, ks = rest & 3, blk = rest >> 2;
    int m = mt * 16 + (lane & 15);
    int k = ks * 32 + ((lane >> 4) << 3) + jj;
    float v = (m < 240 && k < 120) ? bs_w[(size_t)(blk * 240 + m) * 120 + k] : 0.f;
    dst[i] = f2bf(v);
}
__global__ void k_prep_rfrag(const float* __restrict__ br_w, u16* __restrict__ dst) {
    int i = blockIdx.x * 256 + threadIdx.x;
    if (i >= NBLK * 4 * 8 * 512) return;
    int jj = i & 7, lane = (i >> 3) & 63, mt = (i >> 9) & 7;
    int rest = i >> 12, ks = rest & 3, blk = rest >> 2;
    int m = mt * 16 + (lane & 15);
    int k = ks * 32 + ((lane >> 4) << 3) + jj;
    float v = (m < 120 && k < 120) ? br_w[(size_t)(blk * 120 + m) * 120 + k] : 0.f;
    dst[i] = f2bf(v);
}
__global__ void k_prep_h1frag(const float* __restrict__ h1_w, u16* __restrict__ dst) {
    int i = blockIdx.x * 256 + threadIdx.x;
    if (i >= 8 * 16 * 512) return;
    int jj = i & 7, lane = (i >> 3) & 63, mt = (i >> 9) & 15, ks = i >> 13;
    int m = mt * 16 + (lane & 15);
    int k = ks * 32 + ((lane >> 4) << 3) + jj;
    float v = (k < 240) ? h1_w[(size_t)m * 240 + k] : 0.f;
    dst[i] = f2bf(v);
}
__global__ void k_prep_h2frag(const float* __restrict__ h2_w, u16* __restrict__ dst) {
    int i = blockIdx.x * 256 + threadIdx.x;
    if (i >= 8 * 16 * 512) return;
    int jj = i & 7, lane = (i >> 3) & 63, mt = (i >> 9) & 15, ks = i >> 13;
    int m = mt * 16 + (lane & 15);
    int k = ks * 32 + ((lane >> 4) << 3) + jj;
    dst[i] = f2bf(h2_w[(size_t)m * 256 + k]);
}
__global__ void k_prep_upfrag(const float* __restrict__ up_w, u16* __restrict__ dst) {
    int i = blockIdx.x * 256 + threadIdx.x;
    if (i >= 256 * 10 * 5 * 512) return;
    int jj = i & 7, lane = (i >> 3) & 63;
    int rest = i >> 9;
    int mt = rest % 5; rest /= 5;
    int ks = rest % 10; int p = rest / 10;
    int m = mt * 16 + (lane & 15);
    int k = ks * 32 + ((lane >> 4) << 3) + jj;
    int c = k >> 2, j = k & 3;
    int r = (256 - ((p + 1) & 255)) & 255;
    int kk = r + 256 * j;
    float v = (m < 80 && kk < KUP) ? up_w[((size_t)m * 80 + c) * KUP + kk] : 0.f;
    dst[i] = f2bf(v);
}
__global__ void k_prep_zbias(const float* __restrict__ bc_b, const float* __restrict__ bq_b,
                             float* __restrict__ dst) {
    int i = blockIdx.x * 256 + threadIdx.x;
    if (i >= NBLK * 256) return;
    int m = i & 255, blk = i >> 8;
    float v = 0.f;
    if (m < 240) {
        int o = (m & 1) ? (m >> 1) + 120 : (m >> 1);
        v = bc_b[blk * 240 + o] + bq_b[blk * 240 + o];
    }
    dst[i] = v;
}
__global__ void k_prep_skbias(const float* __restrict__ bs_b, float* __restrict__ dst) {
    int i = blockIdx.x * 256 + threadIdx.x;
    if (i >= NBLK * 240) return;
    dst[i] = bs_b[i];
}
__global__ void k_res_initT(const float* __restrict__ wav, const float* __restrict__ in_w,
                            const float* __restrict__ in_b, float* __restrict__ resT) {
    int i = blockIdx.x * 256 + threadIdx.x;
    if (i >= L_LEN * RCH) return;
    int t = i / RCH, c = i % RCH;
    resT[i] = wav[t] * in_w[c] + in_b[c];
}

// ================= upsample (MFMA, per phase p) =================
__global__ __launch_bounds__(256) void k_up(const float* __restrict__ mel,
        const u16* __restrict__ upf, const float* __restrict__ up_b,
        u16* __restrict__ condT) {
    __shared__ u16 s_ms[64 * 328];
    const int tid = threadIdx.x, l = tid & 63, w = tid >> 6;
    const int quad = l >> 4, tloc = l & 15;
    const int p = blockIdx.x, s0 = blockIdx.y * 64;
    for (int rr = 0; rr < 16; rr++) {
        int tt = w + 4 * rr;
        int sg = s0 + tt;
        #pragma unroll
        for (int base = 0; base < 320; base += 64) {
            int ck = base + l;
            int c = ck >> 2, j = ck & 3;
            int mi = 1 + j + sg;
            float v = (mi < 160) ? mel[c * 160 + mi] : 0.f;
            s_ms[tt * 328 + ck] = f2bf(v);
        }
    }
    __syncthreads();
    f32x4 acc[2][4];
    #pragma unroll
    for (int i = 0; i < 2; i++)
        #pragma unroll
        for (int n = 0; n < 4; n++) acc[i][n] = (f32x4){0.f, 0.f, 0.f, 0.f};
    const int nmt = (w == 0) ? 2 : 1;
    int mts[2]; mts[0] = w; mts[1] = 4;
    for (int ks = 0; ks < 10; ks++) {
        short8 b[4];
        int k0 = ks * 32 + quad * 8;
        #pragma unroll
        for (int n = 0; n < 4; n++)
            b[n] = *(const short8*)&s_ms[(n * 16 + tloc) * 328 + k0];
        const short8* ap = (const short8*)(upf) + ((size_t)p * 10 + ks) * 5 * 64;
        for (int i = 0; i < nmt; i++) {
            short8 a = ap[mts[i] * 64 + l];
            #pragma unroll
            for (int n = 0; n < 4; n++) acc[i][n] = MFMA(a, b[n], acc[i][n]);
        }
    }
    for (int i = 0; i < nmt; i++) {
        int o_base = mts[i] * 16 + quad * 4;
        float4 ub = *(const float4*)(up_b + o_base);
        float bb[4] = {ub.x, ub.y, ub.z, ub.w};
        #pragma unroll
        for (int n = 0; n < 4; n++) {
            int sg = s0 + n * 16 + tloc;
            int t = p + 256 * sg;
            if (t < L_LEN) {
                #pragma unroll
                for (int r = 0; r < 4; r++)
                    condT[(size_t)t * 88 + o_base + r] = f2bf(acc[i][n][r] + bb[r]);
            }
        }
    }
}

// ================= WaveNet block (MFMA, 512 thr / 8 waves) =================
__global__ __launch_bounds__(512, 4) void k_block(
        const u16* __restrict__ condT, const float* __restrict__ resT_in,
        float* __restrict__ resT_out, u16* __restrict__ skipT,
        const u16* __restrict__ zfrag, const u16* __restrict__ skfrag,
        const u16* __restrict__ rfrag, const float* __restrict__ zbias,
        const float* __restrict__ skbias, const float* __restrict__ resb,
        int blk, int dil, int first) {
    __shared__ u16 s_x[64 * 328];   // [t][k]; k: 0-119 past, 120-239 cur, 240-319 cond
    u16* s_h = s_x;                 // aliased after barrier: [t][j] stride 136
    const int tid = threadIdx.x, l = tid & 63, w = tid >> 6;  // w 0..7
    const int quad = l >> 4, tloc = l & 15;
    const int t0 = blockIdx.x * 64;
    // prefetch first z A-frags before staging
    const short8* zap = (const short8*)(zfrag) + (size_t)blk * 10 * 16 * 64;
    short8 a_cur[2], a_nxt[2];
    #pragma unroll
    for (int i = 0; i < 2; i++) a_cur[i] = zap[(size_t)(w * 2 + i) * 64 + l];
    // ---- stage X ----
    for (int rr = 0; rr < 8; rr++) {
        int tt = w + 8 * rr;
        int tg = t0 + tt, tp = tg - dil;
        if (l < 60) {
            float2 pv = make_float2(0.f, 0.f), cv = make_float2(0.f, 0.f);
            if (tp >= 0 && tp < L_LEN) pv = *(const float2*)(resT_in + (size_t)tp * 120 + 2 * l);
            if (tg < L_LEN)            cv = *(const float2*)(resT_in + (size_t)tg * 120 + 2 * l);
            *(unsigned*)&s_x[tt * 328 + 2 * l]       = pack2(pv.x, pv.y);
            *(unsigned*)&s_x[tt * 328 + 120 + 2 * l] = pack2(cv.x, cv.y);
        }
        if (l < 40) {
            unsigned q = 0;
            if (tg < L_LEN) q = *(const unsigned*)(condT + (size_t)tg * 88 + 2 * l);
            *(unsigned*)&s_x[tt * 328 + 240 + 2 * l] = q;
        }
    }
    __syncthreads();
    // ---- z GEMM: M=256 (2 mt/wave), K=320, N=64, prefetch pipeline ----
    f32x4 acc[2][4];
    #pragma unroll
    for (int i = 0; i < 2; i++)
        #pragma unroll
        for (int n = 0; n < 4; n++) acc[i][n] = (f32x4){0.f, 0.f, 0.f, 0.f};
    for (int ks = 0; ks < 10; ks++) {
        if (ks < 9) {
            #pragma unroll
            for (int i = 0; i < 2; i++)
                a_nxt[i] = zap[((size_t)(ks + 1) * 16 + w * 2 + i) * 64 + l];
        }
        int k0 = ks * 32 + quad * 8;
        short8 b[4];
        #pragma unroll
        for (int n = 0; n < 4; n++)
            b[n] = *(const short8*)&s_x[(n * 16 + tloc) * 328 + k0];
        #pragma unroll
        for (int i = 0; i < 2; i++)
            #pragma unroll
            for (int n = 0; n < 4; n++) acc[i][n] = MFMA(a_cur[i], b[n], acc[i][n]);
        #pragma unroll
        for (int i = 0; i < 2; i++) a_cur[i] = a_nxt[i];
    }
    // prefetch first skip/res A-frags (overlap gating VALU)
    const short8* sap = (const short8*)(skfrag) + (size_t)blk * 4 * 16 * 64;
    const short8* rap = (const short8*)(rfrag) + (size_t)blk * 4 * 8 * 64;
    short8 sa_c[2], sa_n[2], ra_c, ra_n;
    #pragma unroll
    for (int i = 0; i < 2; i++) sa_c[i] = sap[(size_t)(w * 2 + i) * 64 + l];
    ra_c = rap[(size_t)w * 64 + l];
    // prefetch skip RMW rows (bf16, consumed in epilogue; overlaps everything below)
    uint2 skp[2][4];
    if (!first) {
        #pragma unroll
        for (int i = 0; i < 2; i++) {
            int m_base = (w * 2 + i) * 16 + quad * 4;
            if (m_base < 240) {
                #pragma unroll
                for (int n = 0; n < 4; n++) {
                    int t = t0 + n * 16 + tloc;
                    if (t < L_LEN)
                        skp[i][n] = *(const uint2*)(skipT + (size_t)t * 240 + m_base);
                }
            }
        }
    }
    // ---- gating ----
    unsigned hu[2][4];
    #pragma unroll
    for (int i = 0; i < 2; i++) {
        int m_base = (w * 2 + i) * 16 + quad * 4;
        float4 bz4 = *(const float4*)(zbias + blk * 256 + m_base);
        #pragma unroll
        for (int n = 0; n < 4; n++) {
            float h0 = gate(acc[i][n][0] + bz4.x, acc[i][n][1] + bz4.y);
            float h1 = gate(acc[i][n][2] + bz4.z, acc[i][n][3] + bz4.w);
            hu[i][n] = pack2(h0, h1);
        }
    }
    __syncthreads();  // all z reads of s_x done -> safe to alias as s_h
    #pragma unroll
    for (int i = 0; i < 2; i++) {
        int j0 = (w * 2 + i) * 8 + quad * 2;
        #pragma unroll
        for (int n = 0; n < 4; n++)
            *(unsigned*)&s_h[(n * 16 + tloc) * 136 + j0] = hu[i][n];
    }
    __syncthreads();
    // ---- skip GEMM (2 mt/wave) + res GEMM (1 mt/wave), K=128, N=64 ----
    f32x4 sacc[2][4], racc[4];
    #pragma unroll
    for (int i = 0; i < 2; i++)
        #pragma unroll
        for (int n = 0; n < 4; n++) sacc[i][n] = (f32x4){0.f, 0.f, 0.f, 0.f};
    #pragma unroll
    for (int n = 0; n < 4; n++) racc[n] = (f32x4){0.f, 0.f, 0.f, 0.f};
    for (int ks = 0; ks < 4; ks++) {
        if (ks < 3) {
            #pragma unroll
            for (int i = 0; i < 2; i++)
                sa_n[i] = sap[((size_t)(ks + 1) * 16 + w * 2 + i) * 64 + l];
            ra_n = rap[((size_t)(ks + 1) * 8 + w) * 64 + l];
        }
        short8 b[4];
        int k0 = ks * 32 + quad * 8;
        #pragma unroll
        for (int n = 0; n < 4; n++)
            b[n] = *(const short8*)&s_h[(n * 16 + tloc) * 136 + k0];
        #pragma unroll
        for (int i = 0; i < 2; i++)
            #pragma unroll
            for (int n = 0; n < 4; n++) sacc[i][n] = MFMA(sa_c[i], b[n], sacc[i][n]);
        #pragma unroll
        for (int n = 0; n < 4; n++) racc[n] = MFMA(ra_c, b[n], racc[n]);
        #pragma unroll
        for (int i = 0; i < 2; i++) sa_c[i] = sa_n[i];
        ra_c = ra_n;
    }
    // ---- skip epilogue: bf16 RMW in [L][240] ----
    #pragma unroll
    for (int i = 0; i < 2; i++) {
        int m_base = (w * 2 + i) * 16 + quad * 4;
        if (m_base >= 240) continue;
        float4 sb4 = *(const float4*)(skbias + blk * 240 + m_base);
        #pragma unroll
        for (int n = 0; n < 4; n++) {
            int t = t0 + n * 16 + tloc;
            if (t >= L_LEN) continue;
            float x0 = sacc[i][n][0] + sb4.x;
            float x1 = sacc[i][n][1] + sb4.y;
            float x2 = sacc[i][n][2] + sb4.z;
            float x3 = sacc[i][n][3] + sb4.w;
            if (!first) {
                uint2 pv = skp[i][n];
                x0 += b16tof((u16)(pv.x & 0xFFFF));
                x1 += b16tof((u16)(pv.x >> 16));
                x2 += b16tof((u16)(pv.y & 0xFFFF));
                x3 += b16tof((u16)(pv.y >> 16));
            }
            uint2 ov;
            ov.x = pack2(x0, x1);
            ov.y = pack2(x2, x3);
            *(uint2*)(skipT + (size_t)t * 240 + m_base) = ov;
        }
    }
    // ---- res epilogue ----
    {
        int m_base = w * 16 + quad * 4;
        if (m_base < 120) {
            float4 rb4 = *(const float4*)(resb + blk * 120 + m_base);
            #pragma unroll
            for (int n = 0; n < 4; n++) {
                int t = t0 + n * 16 + tloc;
                if (t >= L_LEN) continue;
                float4 cur = *(const float4*)(resT_in + (size_t)t * 120 + m_base);
                float4 o;
                o.x = cur.x + racc[n][0] + rb4.x;
                o.y = cur.y + racc[n][1] + rb4.y;
                o.z = cur.z + racc[n][2] + rb4.z;
                o.w = cur.w + racc[n][3] + rb4.w;
                *(float4*)(resT_out + (size_t)t * 120 + m_base) = o;
            }
        }
    }
}

// ================= head (MFMA, 512 thr) =================
__global__ __launch_bounds__(512, 4) void k_final(const u16* __restrict__ skipT,
        const u16* __restrict__ h1f, const u16* __restrict__ h2f,
        const float* __restrict__ h1_b, const float* __restrict__ h2_b,
        float* __restrict__ out) {
    __shared__ u16 s_m[64 * 264];
    const int tid = threadIdx.x, l = tid & 63, w = tid >> 6;  // w 0..7
    const int quad = l >> 4, tloc = l & 15;
    const int t0 = blockIdx.x * 64;
    // prefetch first h1 A-frags
    const short8* ap1 = (const short8*)h1f;
    short8 a_cur[2], a_nxt[2];
    #pragma unroll
    for (int i = 0; i < 2; i++) a_cur[i] = ap1[(size_t)(w * 2 + i) * 64 + l];
    // stage relu(skip) from bf16
    for (int rr = 0; rr < 8; rr++) {
        int tt = w + 8 * rr;
        int tg = t0 + tt;
        uint2 v = make_uint2(0u, 0u);
        if (l < 60 && tg < L_LEN)
            v = *(const uint2*)(skipT + (size_t)tg * 240 + 4 * l);
        float x0 = fmaxf(b16tof((u16)(v.x & 0xFFFF)), 0.f);
        float x1 = fmaxf(b16tof((u16)(v.x >> 16)), 0.f);
        float x2 = fmaxf(b16tof((u16)(v.y & 0xFFFF)), 0.f);
        float x3 = fmaxf(b16tof((u16)(v.y >> 16)), 0.f);
        uint2 ov;
        ov.x = pack2(x0, x1);
        ov.y = pack2(x2, x3);
        *(uint2*)&s_m[tt * 264 + 4 * l] = ov;  // l>=60 writes zeros (pad cols 240..255)
    }
    __syncthreads();
    // GEMM h1 (2 mt/wave)
    f32x4 acc[2][4];
    #pragma unroll
    for (int i = 0; i < 2; i++)
        #pragma unroll
        for (int n = 0; n < 4; n++) acc[i][n] = (f32x4){0.f, 0.f, 0.f, 0.f};
    for (int ks = 0; ks < 8; ks++) {
        if (ks < 7) {
            #pragma unroll
            for (int i = 0; i < 2; i++)
                a_nxt[i] = ap1[((size_t)(ks + 1) * 16 + w * 2 + i) * 64 + l];
        }
        short8 b[4];
        int k0 = ks * 32 + quad * 8;
        #pragma unroll
        for (int n = 0; n < 4; n++)
            b[n] = *(const short8*)&s_m[(n * 16 + tloc) * 264 + k0];
        #pragma unroll
        for (int i = 0; i < 2; i++)
            #pragma unroll
            for (int n = 0; n < 4; n++) acc[i][n] = MFMA(a_cur[i], b[n], acc[i][n]);
        #pragma unroll
        for (int i = 0; i < 2; i++) a_cur[i] = a_nxt[i];
    }
    unsigned ylo[2][4], yhi[2][4];
    #pragma unroll
    for (int i = 0; i < 2; i++) {
        int m_base = (w * 2 + i) * 16 + quad * 4;
        float4 b1 = *(const float4*)(h1_b + m_base);
        #pragma unroll
        for (int n = 0; n < 4; n++) {
            float y0 = fmaxf(acc[i][n][0] + b1.x, 0.f);
            float y1v = fmaxf(acc[i][n][1] + b1.y, 0.f);
            float y2 = fmaxf(acc[i][n][2] + b1.z, 0.f);
            float y3 = fmaxf(acc[i][n][3] + b1.w, 0.f);
            ylo[i][n] = pack2(y0, y1v);
            yhi[i][n] = pack2(y2, y3);
        }
    }
    const short8* ap2 = (const short8*)h2f;
    #pragma unroll
    for (int i = 0; i < 2; i++) a_cur[i] = ap2[(size_t)(w * 2 + i) * 64 + l];
    __syncthreads();
    #pragma unroll
    for (int i = 0; i < 2; i++) {
        int m_base = (w * 2 + i) * 16 + quad * 4;
        #pragma unroll
        for (int n = 0; n < 4; n++) {
            int t = n * 16 + tloc;
            *(unsigned*)&s_m[t * 264 + m_base]     = ylo[i][n];
            *(unsigned*)&s_m[t * 264 + m_base + 2] = yhi[i][n];
        }
    }
    __syncthreads();
    // GEMM h2
    #pragma unroll
    for (int i = 0; i < 2; i++)
        #pragma unroll
        for (int n = 0; n < 4; n++) acc[i][n] = (f32x4){0.f, 0.f, 0.f, 0.f};
    for (int ks = 0; ks < 8; ks++) {
        if (ks < 7) {
            #pragma unroll
            for (int i = 0; i < 2; i++)
                a_nxt[i] = ap2[((size_t)(ks + 1) * 16 + w * 2 + i) * 64 + l];
        }
        short8 b[4];
        int k0 = ks * 32 + quad * 8;
        #pragma unroll
        for (int n = 0; n < 4; n++)
            b[n] = *(const short8*)&s_m[(n * 16 + tloc) * 264 + k0];
        #pragma unroll
        for (int i = 0; i < 2; i++)
            #pragma unroll
            for (int n = 0; n < 4; n++) acc[i][n] = MFMA(a_cur[i], b[n], acc[i][n]);
        #pragma unroll
        for (int i = 0; i < 2; i++) a_cur[i] = a_nxt[i];
    }
    #pragma unroll
    for (int i = 0; i < 2; i++) {
        int m_base = (w * 2 + i) * 16 + quad * 4;
        float4 b2 = *(const float4*)(h2_b + m_base);
        float bb[4] = {b2.x, b2.y, b2.z, b2.w};
        #pragma unroll
        for (int n = 0; n < 4; n++) {
            int t = t0 + n * 16 + tloc;
            if (t >= L_LEN) continue;
            #pragma unroll
            for (int r = 0; r < 4; r++)
                out[(size_t)(m_base + r) * L_LEN + t] = acc[i][n][r] + bb[r];
        }
    }
}

extern "C" void kernel_launch(void* const* d_in, const int* in_sizes, int n_in,
                              void* d_out, int out_size, void* d_ws, size_t ws_size,
                              hipStream_t stream) {
    const float* wav   = (const float*)d_in[0];
    const float* mel   = (const float*)d_in[1];
    const float* up_w  = (const float*)d_in[2];
    const float* up_b  = (const float*)d_in[3];
    const float* in_w  = (const float*)d_in[4];
    const float* in_b  = (const float*)d_in[5];
    const float* bc_w  = (const float*)d_in[6];
    const float* bc_b  = (const float*)d_in[7];
    const float* bq_w  = (const float*)d_in[8];
    const float* bq_b  = (const float*)d_in[9];
    const float* bs_w  = (const float*)d_in[10];
    const float* bs_b  = (const float*)d_in[11];
    const float* br_w  = (const float*)d_in[12];
    const float* br_b  = (const float*)d_in[13];
    const float* h1_w  = (const float*)d_in[14];
    const float* h1_b  = (const float*)d_in[15];
    const float* h2_w  = (const float*)d_in[16];
    const float* h2_b  = (const float*)d_in[17];

    char* wsb = (char*)d_ws;
    u16*   condT = (u16*)(wsb + O_CONDT);
    float* resA  = (float*)(wsb + O_RESA);
    float* resB  = (float*)(wsb + O_RESB);
    u16*   skipT = (u16*)(wsb + O_SKIP);
    u16*   zfrag = (u16*)(wsb + O_ZFRAG);
    u16*   skf   = (u16*)(wsb + O_SKF);
    u16*   rf    = (u16*)(wsb + O_RF);
    u16*   h1f   = (u16*)(wsb + O_H1F);
    u16*   h2f   = (u16*)(wsb + O_H2F);
    u16*   upf   = (u16*)(wsb + O_UPF);
    float* zb    = (float*)(wsb + O_ZB);
    float* skb   = (float*)(wsb + O_SKB);

    k_prep_zfrag <<<5120, 256, 0, stream>>>(bc_w, bq_w, zfrag);
    k_prep_skfrag<<<2048, 256, 0, stream>>>(bs_w, skf);
    k_prep_rfrag <<<1024, 256, 0, stream>>>(br_w, rf);
    k_prep_h1frag<<<256, 256, 0, stream>>>(h1_w, h1f);
    k_prep_h2frag<<<256, 256, 0, stream>>>(h2_w, h2f);
    k_prep_upfrag<<<25600, 256, 0, stream>>>(up_w, upf);
    k_prep_zbias <<<16, 256, 0, stream>>>(bc_b, bq_b, zb);
    k_prep_skbias<<<15, 256, 0, stream>>>(bs_b, skb);
    k_res_initT  <<<(L_LEN * RCH + 255) / 256, 256, 0, stream>>>(wav, in_w, in_b, resA);
    k_up<<<dim3(256, 3), 256, 0, stream>>>(mel, upf, up_b, condT);

    for (int i = 0; i < NBLK; i++) {
        int d = 1 << (i & 7);
        const float* rin = (i & 1) ? resB : resA;
        float* rout      = (i & 1) ? resA : resB;
        k_block<<<NT, 512, 0, stream>>>(condT, rin, rout, skipT, zfrag, skf, rf,
                                        zb, skb, br_b, i, d, (i == 0) ? 1 : 0);
    }
    k_final<<<NT, 512, 0, stream>>>(skipT, h1f, h2f, h1_b, h2_b, (float*)d_out);
}